// Round 2
// baseline (2759.946 us; speedup 1.0000x reference)
//
#include <hip/hip_runtime.h>
#include <math.h>

#define T_LEN 256
#define B_SZ  32
#define ZD    64
#define HD    256
#define NSAMP (B_SZ*(T_LEN-1))   // 8160
#define MBLK  16                 // samples per ODE block

// ws layout (float offsets)
#define SZ_P0   ((T_LEN-1)*B_SZ*ZD)     // 522240
#define SZ_ZB   (B_SZ*(T_LEN-1)*ZD)     // 522240
#define SZ_W1   (HD*HD)                 // 65536
#define SZ_W0B  (HD*ZD)                 // 16384
#define OFF_P0  0
#define OFF_ZB  (OFF_P0 + SZ_P0)
#define OFF_W1P (OFF_ZB + SZ_ZB)
#define OFF_W1B (OFF_W1P + SZ_W1)
#define OFF_W0B (OFF_W1B + SZ_W1)

__device__ __forceinline__ float dot4(float4 a, float4 b) {
    return a.x * b.x + a.y * b.y + a.z * b.z + a.w * b.w;
}

// Yoshida coefficients * h_step (h=0.02), drift(+cs[i]*h) / kick(-ds[i]*h) interleaved:
// e%7: 0 drift cs0, 1 kick ds0, 2 drift cs1, 3 kick ds1, 4 drift cs2, 5 kick ds2, 6 drift cs3
__device__ __constant__ float c_coef[7] = {
     0.013512071919596578f,   // +cs0*h
    -0.027024143839193156f,   // -ds0*h (ds0=w1)
    -0.003512071919596575f,   // +cs1*h
     0.034048287678386313f,   // -ds1*h (ds1=w0<0)
    -0.003512071919596575f,   // +cs2*h
    -0.027024143839193156f,   // -ds2*h
     0.013512071919596578f    // +cs3*h
};

// ---------------- prep: pack ODE weights for coalesced per-k4 float4 reads ----
// W1P[(k>>2)*1024 + n*4 + (k&3)] = Wh1[n][k]       (fwd1: thread n iterates k)
// W1B[(n>>2)*1024 + k*4 + (n&3)] = Wh1[n][k]       (bwd1: thread k iterates n)
// W0B[(n>>2)*256  + kk*4 + (n&3)] = Wh0[n][kk]     (bwd0: thread kk iterates n)
__global__ __launch_bounds__(256) void prep_pack(
    const float* __restrict__ Wh1, const float* __restrict__ Wh0,
    float* __restrict__ W1P, float* __restrict__ W1B, float* __restrict__ W0B)
{
    int i = blockIdx.x * 256 + threadIdx.x;      // 0..65535
    int n = i >> 8, k = i & 255;
    float w = Wh1[i];
    W1P[(k >> 2) * 1024 + n * 4 + (k & 3)] = w;
    W1B[(n >> 2) * 1024 + k * 4 + (n & 3)] = w;
    if (i < HD * ZD) {
        int nn = i >> 6, kk = i & 63;
        W0B[(nn >> 2) * 256 + kk * 4 + (nn & 3)] = Wh0[i];
    }
}

// ---------------- P0 = x[:,255-s,:] @ Wih0^T + bih0 + bhh0,  P0[s][b][j] -------
__global__ __launch_bounds__(256) void p0_kernel(
    const float* __restrict__ x, const float* __restrict__ Wih0,
    const float* __restrict__ bih0, const float* __restrict__ bhh0,
    float* __restrict__ P0)
{
    __shared__ float xs[B_SZ * 128];
    int s = blockIdx.x;                 // 0..254
    int t = (T_LEN - 1) - s;
    int tid = threadIdx.x;
    // stage x[:, t, :] (32x128 floats) cooperatively
#pragma unroll
    for (int p = 0; p < 4; ++p) {
        int idx4 = tid + p * 256;            // float4 index
        int b = idx4 >> 5;                   // 32 float4 per row of 128
        int k = (idx4 & 31) * 4;
        *(float4*)&xs[b * 128 + k] = *(const float4*)&x[b * (T_LEN * 128) + t * 128 + k];
    }
    int j = tid & 63, bq = tid >> 6;
    float wr[128];
#pragma unroll
    for (int k4 = 0; k4 < 32; ++k4) {
        float4 v = *(const float4*)&Wih0[j * 128 + k4 * 4];
        wr[k4 * 4 + 0] = v.x; wr[k4 * 4 + 1] = v.y; wr[k4 * 4 + 2] = v.z; wr[k4 * 4 + 3] = v.w;
    }
    float bias = bih0[j] + bhh0[j];
    __syncthreads();
    for (int p = 0; p < 8; ++p) {
        int b = bq * 8 + p;
        float a0 = bias, a1 = 0.f;
#pragma unroll
        for (int k4 = 0; k4 < 32; ++k4) {
            float4 v = *(const float4*)&xs[b * 128 + k4 * 4];
            a0 += v.x * wr[k4 * 4 + 0] + v.y * wr[k4 * 4 + 1];
            a1 += v.z * wr[k4 * 4 + 2] + v.w * wr[k4 * 4 + 3];
        }
        P0[(s * B_SZ + b) * ZD + j] = a0 + a1;
    }
}

// ---------------- RNN scan: 1 block per batch, 1 wave, weights in VGPRs -------
__global__ __launch_bounds__(64, 1) void rnn_kernel(
    const float* __restrict__ P0, const float* __restrict__ h0in,
    const float* __restrict__ Whh0, const float* __restrict__ Wih1,
    const float* __restrict__ Whh1, const float* __restrict__ bih1,
    const float* __restrict__ bhh1,
    float* __restrict__ zbuf, float* __restrict__ out)
{
    __shared__ float h0buf[ZD];
    __shared__ float h1buf[ZD];
    int b = blockIdx.x, j = threadIdx.x;
    float wh0[ZD], wi1[ZD], wh1[ZD];
#pragma unroll
    for (int k4 = 0; k4 < 16; ++k4) {
        float4 v = *(const float4*)&Whh0[j * ZD + k4 * 4];
        wh0[k4*4+0]=v.x; wh0[k4*4+1]=v.y; wh0[k4*4+2]=v.z; wh0[k4*4+3]=v.w;
        v = *(const float4*)&Wih1[j * ZD + k4 * 4];
        wi1[k4*4+0]=v.x; wi1[k4*4+1]=v.y; wi1[k4*4+2]=v.z; wi1[k4*4+3]=v.w;
        v = *(const float4*)&Whh1[j * ZD + k4 * 4];
        wh1[k4*4+0]=v.x; wh1[k4*4+1]=v.y; wh1[k4*4+2]=v.z; wh1[k4*4+3]=v.w;
    }
    float bias1 = bih1[j] + bhh1[j];
    h0buf[j] = h0in[j];
    h1buf[j] = h0in[ZD + j];
    __syncthreads();

    for (int s = 0; s < T_LEN - 1; ++s) {     // s=255 (time 0) never used by output
        float a = P0[(s * B_SZ + b) * ZD + j];
        float acc0 = 0.f, acc1 = 0.f;
#pragma unroll
        for (int k4 = 0; k4 < 16; ++k4) {
            float4 h4 = *(const float4*)&h0buf[k4 * 4];
            acc0 += h4.x * wh0[k4*4+0] + h4.y * wh0[k4*4+1];
            acc1 += h4.z * wh0[k4*4+2] + h4.w * wh0[k4*4+3];
        }
        float hn0 = tanhf(a + acc0 + acc1);
        __syncthreads();
        h0buf[j] = hn0;
        __syncthreads();
        acc0 = bias1; acc1 = 0.f;
#pragma unroll
        for (int k4 = 0; k4 < 16; ++k4) {
            float4 h4 = *(const float4*)&h0buf[k4 * 4];
            acc0 += h4.x * wi1[k4*4+0] + h4.y * wi1[k4*4+1]
                  + h4.z * wi1[k4*4+2] + h4.w * wi1[k4*4+3];
            float4 g4 = *(const float4*)&h1buf[k4 * 4];
            acc1 += g4.x * wh1[k4*4+0] + g4.y * wh1[k4*4+1]
                  + g4.z * wh1[k4*4+2] + g4.w * wh1[k4*4+3];
        }
        float hn1 = tanhf(acc0 + acc1);
        __syncthreads();
        h1buf[j] = hn1;
        __syncthreads();
        int tau = (T_LEN - 2) - s;            // y1[s] == rnn_out[:, tau+1]
        zbuf[(b * (T_LEN - 1) + tau) * ZD + j] = hn1;
        if (s == 0)                            // rnn_out[:, T-1] -> out[:, T-1]
            out[(b * T_LEN + (T_LEN - 1)) * ZD + j] = hn1;
    }
}

// ---------------- ODE: 16 samples/block, 256 threads, 28 grad evals -----------
__global__ __launch_bounds__(256, 2) void ode_kernel(
    const float* __restrict__ zbuf,
    const float* __restrict__ Wh0, const float* __restrict__ bh0,
    const float* __restrict__ bh1, const float* __restrict__ Wout,
    const float* __restrict__ W1P, const float* __restrict__ W1B,
    const float* __restrict__ W0B, float* __restrict__ out)
{
    __shared__ float zq[MBLK][ZD];    // [q(0:32) | p(32:64)]
    __shared__ float h0s[MBLK][HD];   // tanh(h0) fwd, then u (masked bwd vec)
    __shared__ float gs[MBLK][HD];    // Wout*(1-h1^2)
    int tid = threadIdx.x;
    int n = tid;                      // output column 0..255
    int kk = tid & 63, mg = tid >> 6; // bwd0 roles
    int base = blockIdx.x * MBLK;

    float w0r[ZD];                    // Wh0 row n, resident all kernel
#pragma unroll
    for (int k4 = 0; k4 < 16; ++k4) {
        float4 v = *(const float4*)&Wh0[n * ZD + k4 * 4];
        w0r[k4*4+0]=v.x; w0r[k4*4+1]=v.y; w0r[k4*4+2]=v.z; w0r[k4*4+3]=v.w;
    }
    float bh0n = bh0[n], bh1n = bh1[n], woutn = Wout[n];

    {   // load z tile: 16x64 floats
        int m = tid >> 4, c = (tid & 15) * 4;
        *(float4*)&zq[m][c] = *(const float4*)&zbuf[base * ZD + tid * 4];
    }
    __syncthreads();

#pragma unroll 1
    for (int e = 0; e < 28; ++e) {
        int ei = e % 7;
        // ---- Phase A: h0s[m][n] = tanh(bh0[n] + z[m,:].Wh0[n,:]) ----
#pragma unroll 2
        for (int m = 0; m < MBLK; ++m) {
            float a0 = bh0n, a1 = 0.f;
#pragma unroll
            for (int k4 = 0; k4 < 16; ++k4) {
                float4 z4 = *(const float4*)&zq[m][k4 * 4];
                a0 += z4.x * w0r[k4*4+0] + z4.y * w0r[k4*4+1];
                a1 += z4.z * w0r[k4*4+2] + z4.w * w0r[k4*4+3];
            }
            h0s[m][n] = tanhf(a0 + a1);
        }
        __syncthreads();

        // ---- Phase B: gs[m][n] = Wout[n]*(1 - tanh(bh1+h0.Wh1[n,:])^2) ----
        float acc[MBLK];
#pragma unroll
        for (int m = 0; m < MBLK; ++m) acc[m] = bh1n;
#pragma unroll 4
        for (int k4 = 0; k4 < 64; ++k4) {
            float4 w4 = *(const float4*)&W1P[k4 * 1024 + n * 4];
#pragma unroll
            for (int m = 0; m < MBLK; ++m) {
                float4 a4 = *(const float4*)&h0s[m][k4 * 4];
                acc[m] += dot4(a4, w4);
            }
        }
#pragma unroll
        for (int m = 0; m < MBLK; ++m) {
            float h1 = tanhf(acc[m]);
            gs[m][n] = woutn * (1.f - h1 * h1);
        }
        __syncthreads();

        // ---- Phase C: u[m][n] = (gs[m,:].Wh1[:,n]) * (1 - h0s[m][n]^2), in place ----
#pragma unroll
        for (int m = 0; m < MBLK; ++m) acc[m] = 0.f;
#pragma unroll 4
        for (int k4 = 0; k4 < 64; ++k4) {
            float4 w4 = *(const float4*)&W1B[k4 * 1024 + n * 4];
#pragma unroll
            for (int m = 0; m < MBLK; ++m) {
                float4 a4 = *(const float4*)&gs[m][k4 * 4];
                acc[m] += dot4(a4, w4);
            }
        }
#pragma unroll
        for (int m = 0; m < MBLK; ++m) {
            float hv = h0s[m][n];
            h0s[m][n] = acc[m] * (1.f - hv * hv);   // single-owner slot: safe
        }
        __syncthreads();

        // ---- Phase D: dz[m][kk] = u[m,:].Wh0[:,kk]; apply drift/kick to zq ----
        float dz[4] = {0.f, 0.f, 0.f, 0.f};
#pragma unroll 4
        for (int n4 = 0; n4 < 64; ++n4) {
            float4 w4 = *(const float4*)&W0B[n4 * 256 + kk * 4];
#pragma unroll
            for (int jj = 0; jj < 4; ++jj) {
                float4 a4 = *(const float4*)&h0s[mg * 4 + jj][n4 * 4];
                dz[jj] += dot4(a4, w4);
            }
        }
        float cf = c_coef[ei];
        if ((ei & 1) == 0) {            // drift: q += cs*h*dHp (dz[32:64])
            if (kk >= 32) {
#pragma unroll
                for (int jj = 0; jj < 4; ++jj)
                    zq[mg * 4 + jj][kk - 32] += cf * dz[jj];
            }
        } else {                         // kick: p -= ds*h*dHq (dz[0:32])
            if (kk < 32) {
#pragma unroll
                for (int jj = 0; jj < 4; ++jj)
                    zq[mg * 4 + jj][kk + 32] += cf * dz[jj];
            }
        }
        __syncthreads();
    }

    {   // write out[b][tau][:] = z  (sample sidx = b*255 + tau)
        int m = tid >> 4, c = (tid & 15) * 4;
        int sidx = base + m;
        int b = sidx / 255;
        int tau = sidx - b * 255;
        *(float4*)&out[(b * T_LEN + tau) * ZD + c] = *(float4*)&zq[m][c];
    }
}

extern "C" void kernel_launch(void* const* d_in, const int* in_sizes, int n_in,
                              void* d_out, int out_size, void* d_ws, size_t ws_size,
                              hipStream_t stream)
{
    (void)in_sizes; (void)n_in; (void)out_size; (void)ws_size;
    const float* x    = (const float*)d_in[0];
    const float* h0in = (const float*)d_in[1];
    const float* Wih0 = (const float*)d_in[2];
    const float* Whh0 = (const float*)d_in[3];
    const float* bih0 = (const float*)d_in[4];
    const float* bhh0 = (const float*)d_in[5];
    const float* Wih1 = (const float*)d_in[6];
    const float* Whh1 = (const float*)d_in[7];
    const float* bih1 = (const float*)d_in[8];
    const float* bhh1 = (const float*)d_in[9];
    const float* Wh0  = (const float*)d_in[10];
    const float* bh0  = (const float*)d_in[11];
    const float* Wh1  = (const float*)d_in[12];
    const float* bh1  = (const float*)d_in[13];
    const float* Wout = (const float*)d_in[14];
    // d_in[15] = bout (not needed for gradient), d_in[16] = seq_len (fixed 256)

    float* ws  = (float*)d_ws;
    float* P0  = ws + OFF_P0;
    float* zb  = ws + OFF_ZB;
    float* W1P = ws + OFF_W1P;
    float* W1B = ws + OFF_W1B;
    float* W0B = ws + OFF_W0B;
    float* out = (float*)d_out;

    prep_pack<<<256, 256, 0, stream>>>(Wh1, Wh0, W1P, W1B, W0B);
    p0_kernel<<<T_LEN - 1, 256, 0, stream>>>(x, Wih0, bih0, bhh0, P0);
    rnn_kernel<<<B_SZ, 64, 0, stream>>>(P0, h0in, Whh0, Wih1, Whh1, bih1, bhh1, zb, out);
    ode_kernel<<<NSAMP / MBLK, 256, 0, stream>>>(zb, Wh0, bh0, bh1, Wout, W1P, W1B, W0B, out);
}

// Round 3
// 1211.182 us; speedup vs baseline: 2.2787x; 2.2787x over previous
//
#include <hip/hip_runtime.h>
#include <math.h>

#define T_LEN 256
#define B_SZ  32
#define ZD    64
#define HD    256
#define NSAMP (B_SZ*(T_LEN-1))   // 8160
#define MBLK  32                 // samples per ODE block -> 255 blocks

typedef unsigned short u16;
typedef __attribute__((ext_vector_type(8))) __bf16 bf8v;
typedef __attribute__((ext_vector_type(8))) short  s8v;
typedef __attribute__((ext_vector_type(4))) float  f4v;

// ws layout (float offsets). Packs overlay P0 (prep runs AFTER rnn consumed P0).
#define SZ_ZB   (B_SZ*(T_LEN-1)*ZD)     // 522240
#define SZ_P0   ((T_LEN-1)*B_SZ*ZD)     // 522240
#define OFF_ZB  0
#define OFF_P0  (OFF_ZB + SZ_ZB)
// pack offsets in u16 units, based at (u16*)(ws + OFF_P0); total 327680 u16 = 640KB <= P0 region
#define PK_WBH  0
#define PK_WBL  65536
#define PK_WCH  131072
#define PK_WCL  196608
#define PK_WAH  262144
#define PK_WAL  278528
#define PK_WDH  294912
#define PK_WDL  311296

__device__ __forceinline__ float dot4(float4 a, float4 b) {
    return a.x * b.x + a.y * b.y + a.z * b.z + a.w * b.w;
}

__device__ __forceinline__ u16 f2bf(float x) {          // RNE f32->bf16
    unsigned u = __float_as_uint(x);
    unsigned r = (u + 0x7fffu + ((u >> 16) & 1u)) >> 16;
    return (u16)r;
}
__device__ __forceinline__ float bf2f(u16 h) {
    return __uint_as_float(((unsigned)h) << 16);
}
__device__ __forceinline__ float fast_tanh(float x) {
    float xc = fminf(fmaxf(x, -18.f), 18.f);
    float e2 = __builtin_amdgcn_exp2f(xc * 2.8853900817779268f);  // e^(2x)
    return (e2 - 1.f) * __builtin_amdgcn_rcpf(e2 + 1.f);
}
__device__ __forceinline__ f4v mfma16(s8v a, s8v b, f4v c) {
    return __builtin_amdgcn_mfma_f32_16x16x32_bf16(
        __builtin_bit_cast(bf8v, a), __builtin_bit_cast(bf8v, b), c, 0, 0, 0);
}

// Yoshida coefficients * h_step (h=0.02). e%7: even=drift(+cs*h on q from dHp), odd=kick(-ds*h on p from dHq)
__device__ __constant__ float c_coef[7] = {
     0.013512071919596578f,
    -0.027024143839193156f,
    -0.003512071919596575f,
     0.034048287678386313f,
    -0.003512071919596575f,
    -0.027024143839193156f,
     0.013512071919596578f
};

// ---------------- prep: pack weights into MFMA B-fragment order (hi/lo bf16) --
// B-frag elem for tile (nt,ks): lane=g*16+col16, elems i=0..7 -> B[ks*32+8g+i][nt*16+col16]
// pack index = ((nt*KS + ks)*64 + lane)*8 + i
__global__ __launch_bounds__(256) void prep_pack(
    const float* __restrict__ Wh1, const float* __restrict__ Wh0, u16* __restrict__ pk)
{
    int i = blockIdx.x * 256 + threadIdx.x;      // 0..65535
    float w = Wh1[i];
    u16 hi = f2bf(w), lo = f2bf(w - bf2f(hi));
    {   // WB: B[k][n] = Wh1^T[k][n] = Wh1[n][k]; n=i>>8, k=i&255
        int n = i >> 8, k = i & 255;
        int idx = ((((n >> 4) * 8 + (k >> 5)) * 64) + ((k >> 3) & 3) * 16 + (n & 15)) * 8 + (k & 7);
        pk[PK_WBH + idx] = hi; pk[PK_WBL + idx] = lo;
    }
    {   // WC: B[k][n] = Wh1[k][n]; k=i>>8, n=i&255
        int k = i >> 8, n = i & 255;
        int idx = ((((n >> 4) * 8 + (k >> 5)) * 64) + ((k >> 3) & 3) * 16 + (n & 15)) * 8 + (k & 7);
        pk[PK_WCH + idx] = hi; pk[PK_WCL + idx] = lo;
    }
    if (i < HD * ZD) {
        float w0 = Wh0[i];                        // Wh0[256][64]: r=i>>6, c=i&63
        u16 h0i = f2bf(w0), l0i = f2bf(w0 - bf2f(h0i));
        {   // WA: B[k][n] = Wh0^T[k][n] = Wh0[n][k]; n=i>>6, k=i&63 (KS=2)
            int n = i >> 6, k = i & 63;
            int idx = ((((n >> 4) * 2 + (k >> 5)) * 64) + ((k >> 3) & 3) * 16 + (n & 15)) * 8 + (k & 7);
            pk[PK_WAH + idx] = h0i; pk[PK_WAL + idx] = l0i;
        }
        {   // WD: B[k][n] = Wh0[k][n]; k=i>>6, n=i&63 (KS=8, NT=4)
            int k = i >> 6, n = i & 63;
            int idx = ((((n >> 4) * 8 + (k >> 5)) * 64) + ((k >> 3) & 3) * 16 + (n & 15)) * 8 + (k & 7);
            pk[PK_WDH + idx] = h0i; pk[PK_WDL + idx] = l0i;
        }
    }
}

// ---------------- P0 = x[:,255-s,:] @ Wih0^T + bih0 + bhh0,  P0[s][b][j] -------
__global__ __launch_bounds__(256) void p0_kernel(
    const float* __restrict__ x, const float* __restrict__ Wih0,
    const float* __restrict__ bih0, const float* __restrict__ bhh0,
    float* __restrict__ P0)
{
    __shared__ float xs[B_SZ * 128];
    int s = blockIdx.x;
    int t = (T_LEN - 1) - s;
    int tid = threadIdx.x;
#pragma unroll
    for (int p = 0; p < 4; ++p) {
        int idx4 = tid + p * 256;
        int b = idx4 >> 5;
        int k = (idx4 & 31) * 4;
        *(float4*)&xs[b * 128 + k] = *(const float4*)&x[b * (T_LEN * 128) + t * 128 + k];
    }
    int j = tid & 63, bq = tid >> 6;
    float wr[128];
#pragma unroll
    for (int k4 = 0; k4 < 32; ++k4) {
        float4 v = *(const float4*)&Wih0[j * 128 + k4 * 4];
        wr[k4*4+0]=v.x; wr[k4*4+1]=v.y; wr[k4*4+2]=v.z; wr[k4*4+3]=v.w;
    }
    float bias = bih0[j] + bhh0[j];
    __syncthreads();
    for (int p = 0; p < 8; ++p) {
        int b = bq * 8 + p;
        float a0 = bias, a1 = 0.f;
#pragma unroll
        for (int k4 = 0; k4 < 32; ++k4) {
            float4 v = *(const float4*)&xs[b * 128 + k4 * 4];
            a0 += v.x * wr[k4*4+0] + v.y * wr[k4*4+1];
            a1 += v.z * wr[k4*4+2] + v.w * wr[k4*4+3];
        }
        P0[(s * B_SZ + b) * ZD + j] = a0 + a1;
    }
}

// ---------------- RNN scan: 1 block per batch, 1 wave, weights in VGPRs -------
__global__ __launch_bounds__(64, 1) void rnn_kernel(
    const float* __restrict__ P0, const float* __restrict__ h0in,
    const float* __restrict__ Whh0, const float* __restrict__ Wih1,
    const float* __restrict__ Whh1, const float* __restrict__ bih1,
    const float* __restrict__ bhh1,
    float* __restrict__ zbuf, float* __restrict__ out)
{
    __shared__ float h0buf[ZD];
    __shared__ float h1buf[ZD];
    int b = blockIdx.x, j = threadIdx.x;
    float wh0[ZD], wi1[ZD], wh1[ZD];
#pragma unroll
    for (int k4 = 0; k4 < 16; ++k4) {
        float4 v = *(const float4*)&Whh0[j * ZD + k4 * 4];
        wh0[k4*4+0]=v.x; wh0[k4*4+1]=v.y; wh0[k4*4+2]=v.z; wh0[k4*4+3]=v.w;
        v = *(const float4*)&Wih1[j * ZD + k4 * 4];
        wi1[k4*4+0]=v.x; wi1[k4*4+1]=v.y; wi1[k4*4+2]=v.z; wi1[k4*4+3]=v.w;
        v = *(const float4*)&Whh1[j * ZD + k4 * 4];
        wh1[k4*4+0]=v.x; wh1[k4*4+1]=v.y; wh1[k4*4+2]=v.z; wh1[k4*4+3]=v.w;
    }
    float bias1 = bih1[j] + bhh1[j];
    h0buf[j] = h0in[j];
    h1buf[j] = h0in[ZD + j];
    __syncthreads();

    for (int s = 0; s < T_LEN - 1; ++s) {
        float a = P0[(s * B_SZ + b) * ZD + j];
        float acc0 = 0.f, acc1 = 0.f;
#pragma unroll
        for (int k4 = 0; k4 < 16; ++k4) {
            float4 h4 = *(const float4*)&h0buf[k4 * 4];
            acc0 += h4.x * wh0[k4*4+0] + h4.y * wh0[k4*4+1];
            acc1 += h4.z * wh0[k4*4+2] + h4.w * wh0[k4*4+3];
        }
        float hn0 = fast_tanh(a + acc0 + acc1);
        __syncthreads();
        h0buf[j] = hn0;
        __syncthreads();
        acc0 = bias1; acc1 = 0.f;
#pragma unroll
        for (int k4 = 0; k4 < 16; ++k4) {
            float4 h4 = *(const float4*)&h0buf[k4 * 4];
            acc0 += h4.x * wi1[k4*4+0] + h4.y * wi1[k4*4+1]
                  + h4.z * wi1[k4*4+2] + h4.w * wi1[k4*4+3];
            float4 g4 = *(const float4*)&h1buf[k4 * 4];
            acc1 += g4.x * wh1[k4*4+0] + g4.y * wh1[k4*4+1]
                  + g4.z * wh1[k4*4+2] + g4.w * wh1[k4*4+3];
        }
        float hn1 = fast_tanh(acc0 + acc1);
        __syncthreads();
        h1buf[j] = hn1;
        __syncthreads();
        int tau = (T_LEN - 2) - s;
        zbuf[(b * (T_LEN - 1) + tau) * ZD + j] = hn1;
        if (s == 0)
            out[(b * T_LEN + (T_LEN - 1)) * ZD + j] = hn1;
    }
}

// ---------------- ODE: MFMA hi/lo-split, 32 samples/block, 255 blocks ---------
__device__ __forceinline__ s8v lds_frag(const u16* buf, int byt) {
    return *(const s8v*)((const char*)buf + byt);
}
__device__ __forceinline__ void store_hilo(u16* bhi, u16* blo, int byt, float v) {
    u16 hi = f2bf(v);
    *(u16*)((char*)bhi + byt) = hi;
    *(u16*)((char*)blo + byt) = f2bf(v - bf2f(hi));
}

// K=256 GEMM: A from swizzled LDS hi/lo bufs (row stride 512B), B from packed global
__device__ __forceinline__ void gemm_k256(
    const u16* Ah, const u16* Al, const u16* __restrict__ Bh, const u16* __restrict__ Bl,
    int w, int lane, int l15, int lg, f4v acc[2][4])
{
#pragma unroll
    for (int ks = 0; ks < 8; ++ks) {
        s8v ah[2], al[2];
#pragma unroll
        for (int mt = 0; mt < 2; ++mt) {
            int byt = ((mt * 16 + l15) * 512 + ks * 64 + lg * 16) ^ ((l15 & 7) << 4);
            ah[mt] = lds_frag(Ah, byt);
            al[mt] = lds_frag(Al, byt);
        }
#pragma unroll
        for (int j = 0; j < 4; ++j) {
            int off = (((w * 4 + j) * 8 + ks) * 64 + lane) * 8;
            s8v bh = *(const s8v*)(Bh + off);
            s8v bl = *(const s8v*)(Bl + off);
#pragma unroll
            for (int mt = 0; mt < 2; ++mt) {
                acc[mt][j] = mfma16(ah[mt], bh, acc[mt][j]);
                acc[mt][j] = mfma16(al[mt], bh, acc[mt][j]);
                acc[mt][j] = mfma16(ah[mt], bl, acc[mt][j]);
            }
        }
    }
}

__global__ __launch_bounds__(256, 1) void ode_kernel(
    const float* __restrict__ zbuf,
    const float* __restrict__ bh0, const float* __restrict__ bh1,
    const float* __restrict__ Wout, const u16* __restrict__ pk,
    float* __restrict__ out)
{
    __shared__ __align__(16) u16 aAhi[32 * 256], aAlo[32 * 256];
    __shared__ __align__(16) u16 aBhi[32 * 256], aBlo[32 * 256];
    __shared__ __align__(16) u16 zhi[32 * 64],  zlo[32 * 64];
    __shared__ __align__(16) float zq[32 * 64];

    const u16* WBh = pk + PK_WBH; const u16* WBl = pk + PK_WBL;
    const u16* WCh = pk + PK_WCH; const u16* WCl = pk + PK_WCL;
    const u16* WAh = pk + PK_WAH; const u16* WAl = pk + PK_WAL;
    const u16* WDh = pk + PK_WDH; const u16* WDl = pk + PK_WDL;

    const int tid  = threadIdx.x;
    const int w    = tid >> 6, lane = tid & 63;
    const int l15  = lane & 15, lg = lane >> 4;
    const int base = blockIdx.x * MBLK;

    float bh0v[4], bh1v[4], wov[4];
#pragma unroll
    for (int j = 0; j < 4; ++j) {
        int col = (w * 4 + j) * 16 + l15;
        bh0v[j] = bh0[col]; bh1v[j] = bh1[col]; wov[j] = Wout[col];
    }

    // stage z tile -> zq (f32) + zhi/zlo (swizzled bf16 hi/lo)
#pragma unroll
    for (int rep = 0; rep < 2; ++rep) {
        int idx = tid + rep * 256;
        int m = idx >> 4, c4 = idx & 15;
        float4 v = *(const float4*)&zbuf[(size_t)(base + m) * ZD + c4 * 4];
        *(float4*)&zq[m * 64 + c4 * 4] = v;
        ushort4 hh, ll;
        hh.x = f2bf(v.x); ll.x = f2bf(v.x - bf2f(hh.x));
        hh.y = f2bf(v.y); ll.y = f2bf(v.y - bf2f(hh.y));
        hh.z = f2bf(v.z); ll.z = f2bf(v.z - bf2f(hh.z));
        hh.w = f2bf(v.w); ll.w = f2bf(v.w - bf2f(hh.w));
        int byt = (m * 128 + c4 * 8) ^ ((m & 7) << 4);
        *(ushort4*)((char*)zhi + byt) = hh;
        *(ushort4*)((char*)zlo + byt) = ll;
    }
    __syncthreads();

#pragma unroll 1
    for (int e = 0; e < 28; ++e) {
        int ei = e % 7;
        f4v acc[2][4];
#pragma unroll
        for (int mt = 0; mt < 2; ++mt)
#pragma unroll
            for (int j = 0; j < 4; ++j) acc[mt][j] = f4v{0.f, 0.f, 0.f, 0.f};

        // ---- Phase A: pre0 = z @ Wh0^T (K=64) ----
#pragma unroll
        for (int ks = 0; ks < 2; ++ks) {
            s8v ah[2], al[2];
#pragma unroll
            for (int mt = 0; mt < 2; ++mt) {
                int byt = ((mt * 16 + l15) * 128 + ks * 64 + lg * 16) ^ ((l15 & 7) << 4);
                ah[mt] = lds_frag(zhi, byt);
                al[mt] = lds_frag(zlo, byt);
            }
#pragma unroll
            for (int j = 0; j < 4; ++j) {
                int off = (((w * 4 + j) * 2 + ks) * 64 + lane) * 8;
                s8v bh = *(const s8v*)(WAh + off);
                s8v bl = *(const s8v*)(WAl + off);
#pragma unroll
                for (int mt = 0; mt < 2; ++mt) {
                    acc[mt][j] = mfma16(ah[mt], bh, acc[mt][j]);
                    acc[mt][j] = mfma16(al[mt], bh, acc[mt][j]);
                    acc[mt][j] = mfma16(ah[mt], bl, acc[mt][j]);
                }
            }
        }
        float h0reg[2][4][4];
#pragma unroll
        for (int mt = 0; mt < 2; ++mt)
#pragma unroll
            for (int j = 0; j < 4; ++j)
#pragma unroll
                for (int r = 0; r < 4; ++r) {
                    float t = fast_tanh(acc[mt][j][r] + bh0v[j]);
                    h0reg[mt][j][r] = t;
                    int row = mt * 16 + lg * 4 + r;
                    int col = (w * 4 + j) * 16 + l15;
                    int byt = (row * 512 + col * 2) ^ ((row & 7) << 4);
                    store_hilo(aAhi, aAlo, byt, t);
                }
        __syncthreads();

        // ---- Phase B: pre1 = h0 @ Wh1^T; g = Wout*(1-tanh^2) ----
#pragma unroll
        for (int mt = 0; mt < 2; ++mt)
#pragma unroll
            for (int j = 0; j < 4; ++j) acc[mt][j] = f4v{0.f, 0.f, 0.f, 0.f};
        gemm_k256(aAhi, aAlo, WBh, WBl, w, lane, l15, lg, acc);
#pragma unroll
        for (int mt = 0; mt < 2; ++mt)
#pragma unroll
            for (int j = 0; j < 4; ++j)
#pragma unroll
                for (int r = 0; r < 4; ++r) {
                    float t = fast_tanh(acc[mt][j][r] + bh1v[j]);
                    float g = wov[j] * (1.f - t * t);
                    int row = mt * 16 + lg * 4 + r;
                    int col = (w * 4 + j) * 16 + l15;
                    int byt = (row * 512 + col * 2) ^ ((row & 7) << 4);
                    store_hilo(aBhi, aBlo, byt, g);
                }
        __syncthreads();

        // ---- Phase C: u = (g @ Wh1) * (1 - h0^2) ----
#pragma unroll
        for (int mt = 0; mt < 2; ++mt)
#pragma unroll
            for (int j = 0; j < 4; ++j) acc[mt][j] = f4v{0.f, 0.f, 0.f, 0.f};
        gemm_k256(aBhi, aBlo, WCh, WCl, w, lane, l15, lg, acc);
#pragma unroll
        for (int mt = 0; mt < 2; ++mt)
#pragma unroll
            for (int j = 0; j < 4; ++j)
#pragma unroll
                for (int r = 0; r < 4; ++r) {
                    float h = h0reg[mt][j][r];
                    float u = acc[mt][j][r] * (1.f - h * h);
                    int row = mt * 16 + lg * 4 + r;
                    int col = (w * 4 + j) * 16 + l15;
                    int byt = (row * 512 + col * 2) ^ ((row & 7) << 4);
                    store_hilo(aAhi, aAlo, byt, u);
                }
        __syncthreads();

        // ---- Phase D: dz = u @ Wh0 (N=64, wave w owns cols w*16..w*16+15) ----
        f4v accd[2];
        accd[0] = f4v{0.f, 0.f, 0.f, 0.f};
        accd[1] = f4v{0.f, 0.f, 0.f, 0.f};
#pragma unroll
        for (int ks = 0; ks < 8; ++ks) {
            s8v ah[2], al[2];
#pragma unroll
            for (int mt = 0; mt < 2; ++mt) {
                int byt = ((mt * 16 + l15) * 512 + ks * 64 + lg * 16) ^ ((l15 & 7) << 4);
                ah[mt] = lds_frag(aAhi, byt);
                al[mt] = lds_frag(aAlo, byt);
            }
            int off = ((w * 8 + ks) * 64 + lane) * 8;
            s8v bh = *(const s8v*)(WDh + off);
            s8v bl = *(const s8v*)(WDl + off);
#pragma unroll
            for (int mt = 0; mt < 2; ++mt) {
                accd[mt] = mfma16(ah[mt], bh, accd[mt]);
                accd[mt] = mfma16(al[mt], bh, accd[mt]);
                accd[mt] = mfma16(ah[mt], bl, accd[mt]);
            }
        }
        {
            float cf = c_coef[ei];
            int col = w * 16 + l15;
            bool drift = (ei & 1) == 0;
            bool active = drift ? (col >= 32) : (col < 32);
            int dcol = drift ? (col - 32) : (col + 32);
            if (active) {
#pragma unroll
                for (int mt = 0; mt < 2; ++mt)
#pragma unroll
                    for (int r = 0; r < 4; ++r) {
                        int row = mt * 16 + lg * 4 + r;
                        float nz = zq[row * 64 + dcol] + cf * accd[mt][r];
                        zq[row * 64 + dcol] = nz;
                        int byt = (row * 128 + dcol * 2) ^ ((row & 7) << 4);
                        store_hilo(zhi, zlo, byt, nz);
                    }
            }
        }
        __syncthreads();
    }

    // write out[b][tau][:] = z
#pragma unroll
    for (int rep = 0; rep < 2; ++rep) {
        int idx = tid + rep * 256;
        int m = idx >> 4, c4 = idx & 15;
        int sidx = base + m;
        int b = sidx / 255;
        int tau = sidx - b * 255;
        float4 v = *(const float4*)&zq[m * 64 + c4 * 4];
        *(float4*)&out[((size_t)(b * T_LEN + tau)) * ZD + c4 * 4] = v;
    }
}

extern "C" void kernel_launch(void* const* d_in, const int* in_sizes, int n_in,
                              void* d_out, int out_size, void* d_ws, size_t ws_size,
                              hipStream_t stream)
{
    (void)in_sizes; (void)n_in; (void)out_size; (void)ws_size;
    const float* x    = (const float*)d_in[0];
    const float* h0in = (const float*)d_in[1];
    const float* Wih0 = (const float*)d_in[2];
    const float* Whh0 = (const float*)d_in[3];
    const float* bih0 = (const float*)d_in[4];
    const float* bhh0 = (const float*)d_in[5];
    const float* Wih1 = (const float*)d_in[6];
    const float* Whh1 = (const float*)d_in[7];
    const float* bih1 = (const float*)d_in[8];
    const float* bhh1 = (const float*)d_in[9];
    const float* Wh0  = (const float*)d_in[10];
    const float* bh0  = (const float*)d_in[11];
    const float* Wh1  = (const float*)d_in[12];
    const float* bh1  = (const float*)d_in[13];
    const float* Wout = (const float*)d_in[14];

    float* ws = (float*)d_ws;
    float* zb = ws + OFF_ZB;
    float* P0 = ws + OFF_P0;
    u16*   pk = (u16*)(ws + OFF_P0);   // overlays P0, written after rnn consumed it
    float* out = (float*)d_out;

    p0_kernel<<<T_LEN - 1, 256, 0, stream>>>(x, Wih0, bih0, bhh0, P0);
    rnn_kernel<<<B_SZ, 64, 0, stream>>>(P0, h0in, Whh0, Wih1, Whh1, bih1, bhh1, zb, out);
    prep_pack<<<256, 256, 0, stream>>>(Wh1, Wh0, pk);
    ode_kernel<<<NSAMP / MBLK, 256, 0, stream>>>(zb, bh0, bh1, Wout, pk, out);
}

// Round 4
// 372.714 us; speedup vs baseline: 7.4050x; 3.2496x over previous
//
#include <hip/hip_runtime.h>
#include <math.h>

#define T_LEN 256
#define B_SZ  32
#define ZD    64
#define HD    256
#define NSAMP (B_SZ*(T_LEN-1))   // 8160
#define MBLK  32                 // samples per ODE block -> 255 blocks

typedef unsigned short u16;
typedef __attribute__((ext_vector_type(8))) _Float16 h8v;
typedef __attribute__((ext_vector_type(8))) unsigned short us8v;
typedef __attribute__((ext_vector_type(4))) float  f4v;

// ws layout (float offsets). Packs overlay P0 (prep runs AFTER rnn consumed P0).
#define SZ_ZB   (B_SZ*(T_LEN-1)*ZD)     // 522240
#define SZ_P0   ((T_LEN-1)*B_SZ*ZD)     // 522240
#define OFF_ZB  0
#define OFF_P0  (OFF_ZB + SZ_ZB)
// fp16 pack offsets in u16 units, based at (u16*)(ws + OFF_P0); 163840 u16 = 320KB <= P0 region
#define PK_WB  0         // Wh1^T fragments (phase B), 65536
#define PK_WC  65536     // Wh1 fragments (phase C), 65536
#define PK_WA  131072    // Wh0^T fragments (phase A), 16384
#define PK_WD  147456    // Wh0 fragments (phase D), 16384

__device__ __forceinline__ u16 f2h(float x) {
    _Float16 h = (_Float16)x;
    return __builtin_bit_cast(u16, h);
}
__device__ __forceinline__ float fast_tanh(float x) {
    float xc = fminf(fmaxf(x, -18.f), 18.f);
    float e2 = __builtin_amdgcn_exp2f(xc * 2.8853900817779268f);  // e^(2x)
    return (e2 - 1.f) * __builtin_amdgcn_rcpf(e2 + 1.f);
}
__device__ __forceinline__ f4v mfma16h(h8v a, h8v b, f4v c) {
    return __builtin_amdgcn_mfma_f32_16x16x32_f16(a, b, c, 0, 0, 0);
}
__device__ __forceinline__ h8v lds_frag(const u16* buf, int byt) {
    return *(const h8v*)((const char*)buf + byt);
}
__device__ __forceinline__ void store_h(u16* buf, int byt, float v) {
    *(u16*)((char*)buf + byt) = f2h(v);
}

// Yoshida coefficients * h_step (h=0.02). e%7: even=drift(+cs*h on q from dHp), odd=kick(-ds*h on p from dHq)
__device__ __constant__ float c_coef[7] = {
     0.013512071919596578f,
    -0.027024143839193156f,
    -0.003512071919596575f,
     0.034048287678386313f,
    -0.003512071919596575f,
    -0.027024143839193156f,
     0.013512071919596578f
};

// ---------------- prep: pack fp16 weights into MFMA B-fragment order ----------
// frag (nt,ks): lane = lg*16+col16 holds B[ks*32+lg*8+i][nt*16+col16], i=0..7
// idx = ((nt*KS + ks)*64 + lane)*8 + i
__global__ __launch_bounds__(256) void prep_pack(
    const float* __restrict__ Wh1, const float* __restrict__ Wh0, u16* __restrict__ pk)
{
    int i = blockIdx.x * 256 + threadIdx.x;      // 0..65535
    u16 h = f2h(Wh1[i]);
    {   // WB: B[k][n] = Wh1[n][k]; n=i>>8, k=i&255 (KS=8)
        int n = i >> 8, k = i & 255;
        int idx = ((((n >> 4) * 8 + (k >> 5)) * 64) + ((k >> 3) & 3) * 16 + (n & 15)) * 8 + (k & 7);
        pk[PK_WB + idx] = h;
    }
    {   // WC: B[k][n] = Wh1[k][n]; k=i>>8, n=i&255 (KS=8)
        int k = i >> 8, n = i & 255;
        int idx = ((((n >> 4) * 8 + (k >> 5)) * 64) + ((k >> 3) & 3) * 16 + (n & 15)) * 8 + (k & 7);
        pk[PK_WC + idx] = h;
    }
    if (i < HD * ZD) {
        u16 h0 = f2h(Wh0[i]);                    // Wh0[256][64]
        {   // WA: B[k][n] = Wh0[n][k]; n=i>>6 (0..255), k=i&63 (KS=2)
            int n = i >> 6, k = i & 63;
            int idx = ((((n >> 4) * 2 + (k >> 5)) * 64) + ((k >> 3) & 3) * 16 + (n & 15)) * 8 + (k & 7);
            pk[PK_WA + idx] = h0;
        }
        {   // WD: B[k][n] = Wh0[k][n]; k=i>>6, n=i&63 (KS=8, NT=4)
            int k = i >> 6, n = i & 63;
            int idx = ((((n >> 4) * 8 + (k >> 5)) * 64) + ((k >> 3) & 3) * 16 + (n & 15)) * 8 + (k & 7);
            pk[PK_WD + idx] = h0;
        }
    }
}

// ---------------- P0 = x[:,255-s,:] @ Wih0^T + bih0 + bhh0,  P0[s][b][j] -------
__global__ __launch_bounds__(256) void p0_kernel(
    const float* __restrict__ x, const float* __restrict__ Wih0,
    const float* __restrict__ bih0, const float* __restrict__ bhh0,
    float* __restrict__ P0)
{
    __shared__ float xs[B_SZ * 128];
    int s = blockIdx.x;
    int t = (T_LEN - 1) - s;
    int tid = threadIdx.x;
#pragma unroll
    for (int p = 0; p < 4; ++p) {
        int idx4 = tid + p * 256;
        int b = idx4 >> 5;
        int k = (idx4 & 31) * 4;
        *(float4*)&xs[b * 128 + k] = *(const float4*)&x[b * (T_LEN * 128) + t * 128 + k];
    }
    int j = tid & 63, bq = tid >> 6;
    float wr[128];
#pragma unroll
    for (int k4 = 0; k4 < 32; ++k4) {
        float4 v = *(const float4*)&Wih0[j * 128 + k4 * 4];
        wr[k4*4+0]=v.x; wr[k4*4+1]=v.y; wr[k4*4+2]=v.z; wr[k4*4+3]=v.w;
    }
    float bias = bih0[j] + bhh0[j];
    __syncthreads();
    for (int p = 0; p < 8; ++p) {
        int b = bq * 8 + p;
        float a0 = bias, a1 = 0.f;
#pragma unroll
        for (int k4 = 0; k4 < 32; ++k4) {
            float4 v = *(const float4*)&xs[b * 128 + k4 * 4];
            a0 += v.x * wr[k4*4+0] + v.y * wr[k4*4+1];
            a1 += v.z * wr[k4*4+2] + v.w * wr[k4*4+3];
        }
        P0[(s * B_SZ + b) * ZD + j] = a0 + a1;
    }
}

// ---------------- RNN scan: 1 block per batch, 1 wave, weights in VGPRs -------
__global__ __launch_bounds__(64, 1) void rnn_kernel(
    const float* __restrict__ P0, const float* __restrict__ h0in,
    const float* __restrict__ Whh0, const float* __restrict__ Wih1,
    const float* __restrict__ Whh1, const float* __restrict__ bih1,
    const float* __restrict__ bhh1,
    float* __restrict__ zbuf, float* __restrict__ out)
{
    __shared__ float h0buf[ZD];
    __shared__ float h1buf[ZD];
    int b = blockIdx.x, j = threadIdx.x;
    float wh0[ZD], wi1[ZD], wh1[ZD];
#pragma unroll
    for (int k4 = 0; k4 < 16; ++k4) {
        float4 v = *(const float4*)&Whh0[j * ZD + k4 * 4];
        wh0[k4*4+0]=v.x; wh0[k4*4+1]=v.y; wh0[k4*4+2]=v.z; wh0[k4*4+3]=v.w;
        v = *(const float4*)&Wih1[j * ZD + k4 * 4];
        wi1[k4*4+0]=v.x; wi1[k4*4+1]=v.y; wi1[k4*4+2]=v.z; wi1[k4*4+3]=v.w;
        v = *(const float4*)&Whh1[j * ZD + k4 * 4];
        wh1[k4*4+0]=v.x; wh1[k4*4+1]=v.y; wh1[k4*4+2]=v.z; wh1[k4*4+3]=v.w;
    }
    float bias1 = bih1[j] + bhh1[j];
    h0buf[j] = h0in[j];
    h1buf[j] = h0in[ZD + j];
    __syncthreads();

    float a_cur = P0[(0 * B_SZ + b) * ZD + j];
    for (int s = 0; s < T_LEN - 1; ++s) {
        float a_nxt = (s < T_LEN - 2) ? P0[((s + 1) * B_SZ + b) * ZD + j] : 0.f;
        float c0 = 0.f, c1 = 0.f, c2 = 0.f, c3 = 0.f;
#pragma unroll
        for (int k4 = 0; k4 < 16; ++k4) {
            float4 h4 = *(const float4*)&h0buf[k4 * 4];
            c0 += h4.x * wh0[k4*4+0]; c1 += h4.y * wh0[k4*4+1];
            c2 += h4.z * wh0[k4*4+2]; c3 += h4.w * wh0[k4*4+3];
        }
        float hn0 = fast_tanh(a_cur + (c0 + c1) + (c2 + c3));
        a_cur = a_nxt;
        __syncthreads();
        h0buf[j] = hn0;
        __syncthreads();
        c0 = bias1; c1 = 0.f; c2 = 0.f; c3 = 0.f;
#pragma unroll
        for (int k4 = 0; k4 < 16; ++k4) {
            float4 h4 = *(const float4*)&h0buf[k4 * 4];
            c0 += h4.x * wi1[k4*4+0]; c1 += h4.y * wi1[k4*4+1];
            c2 += h4.z * wi1[k4*4+2]; c3 += h4.w * wi1[k4*4+3];
            float4 g4 = *(const float4*)&h1buf[k4 * 4];
            c0 += g4.x * wh1[k4*4+0]; c1 += g4.y * wh1[k4*4+1];
            c2 += g4.z * wh1[k4*4+2]; c3 += g4.w * wh1[k4*4+3];
        }
        float hn1 = fast_tanh((c0 + c1) + (c2 + c3));
        __syncthreads();
        h1buf[j] = hn1;
        __syncthreads();
        int tau = (T_LEN - 2) - s;
        zbuf[(b * (T_LEN - 1) + tau) * ZD + j] = hn1;
        if (s == 0)
            out[(b * T_LEN + (T_LEN - 1)) * ZD + j] = hn1;
    }
}

// ---------------- ODE: fp16 MFMA, weights resident (VGPR+LDS), 512 thr --------
__global__ __launch_bounds__(512, 1) void ode_kernel(
    const float* __restrict__ zbuf,
    const float* __restrict__ bh0, const float* __restrict__ bh1,
    const float* __restrict__ Wout, const u16* __restrict__ pk,
    float* __restrict__ out)
{
    __shared__ __align__(16) u16 sWA[16384];   // 32KB, WA frags
    __shared__ __align__(16) u16 sWD[16384];   // 32KB, WD frags
    __shared__ __align__(16) u16 aA[32 * 256]; // 16KB, swizzled fp16 activations
    __shared__ __align__(16) u16 aB[32 * 256]; // 16KB
    __shared__ __align__(16) u16 zh[32 * 64];  // 4KB, swizzled fp16 z
    __shared__ __align__(16) float zq[32 * 64];// 8KB, fp32 z state

    const int tid  = threadIdx.x;
    const int w    = tid >> 6, lane = tid & 63;
    const int l15  = lane & 15, lg = lane >> 4;
    const int base = blockIdx.x * MBLK;

    // ---- load Wh1 fragments into VGPRs (per wave: 2 nt-tiles each for B and C)
    h8v regWB[2][8], regWC[2][8];
    {
        const h8v* pWB = (const h8v*)(pk + PK_WB);
        const h8v* pWC = (const h8v*)(pk + PK_WC);
#pragma unroll
        for (int t = 0; t < 2; ++t)
#pragma unroll
            for (int ks = 0; ks < 8; ++ks) {
                int fi = ((w * 2 + t) * 8 + ks) * 64 + lane;
                regWB[t][ks] = pWB[fi];
                regWC[t][ks] = pWC[fi];
            }
    }
    // ---- stage WA/WD into LDS (pack order)
    {
        const us8v* gA = (const us8v*)(pk + PK_WA);
        const us8v* gD = (const us8v*)(pk + PK_WD);
#pragma unroll
        for (int r = 0; r < 4; ++r) {
            int idx = tid + r * 512;             // 2048 vec8 per 32KB
            ((us8v*)sWA)[idx] = gA[idx];
            ((us8v*)sWD)[idx] = gD[idx];
        }
    }

    float bh0v[2], bh1v[2], wov[2];
#pragma unroll
    for (int t = 0; t < 2; ++t) {
        int col = (w * 2 + t) * 16 + l15;
        bh0v[t] = bh0[col]; bh1v[t] = bh1[col]; wov[t] = Wout[col];
    }

    // ---- stage z tile (32x64): zq f32 + zh swizzled fp16
    {
        int m = tid >> 4, c4 = tid & 15;
        float4 v = *(const float4*)&zbuf[(size_t)(base + m) * ZD + c4 * 4];
        *(float4*)&zq[m * 64 + c4 * 4] = v;
        ushort4 hh;
        hh.x = f2h(v.x); hh.y = f2h(v.y); hh.z = f2h(v.z); hh.w = f2h(v.w);
        int byt = (m * 128 + c4 * 8) ^ ((m & 7) << 4);
        *(ushort4*)((char*)zh + byt) = hh;
    }
    __syncthreads();

#pragma unroll 1
    for (int e = 0; e < 28; ++e) {
        int ei = e % 7;
        f4v acc[2][2];
#pragma unroll
        for (int mt = 0; mt < 2; ++mt)
#pragma unroll
            for (int t = 0; t < 2; ++t) acc[mt][t] = f4v{0.f, 0.f, 0.f, 0.f};

        // ---- Phase A: pre0 = z @ Wh0^T (K=64, N=256; wave w owns nt=2w,2w+1)
#pragma unroll
        for (int ks = 0; ks < 2; ++ks) {
            h8v az[2];
#pragma unroll
            for (int mt = 0; mt < 2; ++mt) {
                int byt = ((mt * 16 + l15) * 128 + ks * 64 + lg * 16) ^ ((l15 & 7) << 4);
                az[mt] = lds_frag(zh, byt);
            }
#pragma unroll
            for (int t = 0; t < 2; ++t) {
                h8v bw = lds_frag(sWA, (((w * 2 + t) * 2 + ks) * 64 + lane) * 16);
#pragma unroll
                for (int mt = 0; mt < 2; ++mt)
                    acc[mt][t] = mfma16h(az[mt], bw, acc[mt][t]);
            }
        }
        float h0reg[2][2][4];
#pragma unroll
        for (int mt = 0; mt < 2; ++mt)
#pragma unroll
            for (int t = 0; t < 2; ++t)
#pragma unroll
                for (int r = 0; r < 4; ++r) {
                    float tv = fast_tanh(acc[mt][t][r] + bh0v[t]);
                    h0reg[mt][t][r] = tv;
                    int row = mt * 16 + lg * 4 + r;
                    int col = (w * 2 + t) * 16 + l15;
                    store_h(aA, (row * 512 + col * 2) ^ ((row & 7) << 4), tv);
                }
        __syncthreads();

        // ---- Phase B: pre1 = h0 @ Wh1^T; g = Wout*(1-tanh^2)
#pragma unroll
        for (int mt = 0; mt < 2; ++mt)
#pragma unroll
            for (int t = 0; t < 2; ++t) acc[mt][t] = f4v{0.f, 0.f, 0.f, 0.f};
#pragma unroll
        for (int ks = 0; ks < 8; ++ks) {
            h8v ah[2];
#pragma unroll
            for (int mt = 0; mt < 2; ++mt) {
                int byt = ((mt * 16 + l15) * 512 + ks * 64 + lg * 16) ^ ((l15 & 7) << 4);
                ah[mt] = lds_frag(aA, byt);
            }
#pragma unroll
            for (int t = 0; t < 2; ++t)
#pragma unroll
                for (int mt = 0; mt < 2; ++mt)
                    acc[mt][t] = mfma16h(ah[mt], regWB[t][ks], acc[mt][t]);
        }
#pragma unroll
        for (int mt = 0; mt < 2; ++mt)
#pragma unroll
            for (int t = 0; t < 2; ++t)
#pragma unroll
                for (int r = 0; r < 4; ++r) {
                    float tv = fast_tanh(acc[mt][t][r] + bh1v[t]);
                    float g = wov[t] * (1.f - tv * tv);
                    int row = mt * 16 + lg * 4 + r;
                    int col = (w * 2 + t) * 16 + l15;
                    store_h(aB, (row * 512 + col * 2) ^ ((row & 7) << 4), g);
                }
        __syncthreads();

        // ---- Phase C: u = (g @ Wh1) * (1 - h0^2), overwrite aA
#pragma unroll
        for (int mt = 0; mt < 2; ++mt)
#pragma unroll
            for (int t = 0; t < 2; ++t) acc[mt][t] = f4v{0.f, 0.f, 0.f, 0.f};
#pragma unroll
        for (int ks = 0; ks < 8; ++ks) {
            h8v ah[2];
#pragma unroll
            for (int mt = 0; mt < 2; ++mt) {
                int byt = ((mt * 16 + l15) * 512 + ks * 64 + lg * 16) ^ ((l15 & 7) << 4);
                ah[mt] = lds_frag(aB, byt);
            }
#pragma unroll
            for (int t = 0; t < 2; ++t)
#pragma unroll
                for (int mt = 0; mt < 2; ++mt)
                    acc[mt][t] = mfma16h(ah[mt], regWC[t][ks], acc[mt][t]);
        }
#pragma unroll
        for (int mt = 0; mt < 2; ++mt)
#pragma unroll
            for (int t = 0; t < 2; ++t)
#pragma unroll
                for (int r = 0; r < 4; ++r) {
                    float hv = h0reg[mt][t][r];
                    float u = acc[mt][t][r] * (1.f - hv * hv);
                    int row = mt * 16 + lg * 4 + r;
                    int col = (w * 2 + t) * 16 + l15;
                    store_h(aA, (row * 512 + col * 2) ^ ((row & 7) << 4), u);
                }
        __syncthreads();

        // ---- Phase D (waves 4-7): dz = u @ Wh0 (N=64); update zq/zh
        if (w >= 4) {
            int nt = w - 4;
            f4v accd[2];
            accd[0] = f4v{0.f, 0.f, 0.f, 0.f};
            accd[1] = f4v{0.f, 0.f, 0.f, 0.f};
#pragma unroll
            for (int ks = 0; ks < 8; ++ks) {
                h8v ah[2];
#pragma unroll
                for (int mt = 0; mt < 2; ++mt) {
                    int byt = ((mt * 16 + l15) * 512 + ks * 64 + lg * 16) ^ ((l15 & 7) << 4);
                    ah[mt] = lds_frag(aA, byt);
                }
                h8v bw = lds_frag(sWD, ((nt * 8 + ks) * 64 + lane) * 16);
#pragma unroll
                for (int mt = 0; mt < 2; ++mt)
                    accd[mt] = mfma16h(ah[mt], bw, accd[mt]);
            }
            float cf = c_coef[ei];
            int col = nt * 16 + l15;
            bool drift = (ei & 1) == 0;
            bool active = drift ? (col >= 32) : (col < 32);
            int dcol = drift ? (col - 32) : (col + 32);
            if (active) {
#pragma unroll
                for (int mt = 0; mt < 2; ++mt)
#pragma unroll
                    for (int r = 0; r < 4; ++r) {
                        int row = mt * 16 + lg * 4 + r;
                        float nz = zq[row * 64 + dcol] + cf * accd[mt][r];
                        zq[row * 64 + dcol] = nz;
                        store_h(zh, (row * 128 + dcol * 2) ^ ((row & 7) << 4), nz);
                    }
            }
        }
        __syncthreads();
    }

    // ---- write out[b][tau][:] = z
    {
        int m = tid >> 4, c4 = tid & 15;
        int sidx = base + m;
        int b = sidx / 255;
        int tau = sidx - b * 255;
        float4 v = *(const float4*)&zq[m * 64 + c4 * 4];
        *(float4*)&out[((size_t)(b * T_LEN + tau)) * ZD + c4 * 4] = v;
    }
}

extern "C" void kernel_launch(void* const* d_in, const int* in_sizes, int n_in,
                              void* d_out, int out_size, void* d_ws, size_t ws_size,
                              hipStream_t stream)
{
    (void)in_sizes; (void)n_in; (void)out_size; (void)ws_size;
    const float* x    = (const float*)d_in[0];
    const float* h0in = (const float*)d_in[1];
    const float* Wih0 = (const float*)d_in[2];
    const float* Whh0 = (const float*)d_in[3];
    const float* bih0 = (const float*)d_in[4];
    const float* bhh0 = (const float*)d_in[5];
    const float* Wih1 = (const float*)d_in[6];
    const float* Whh1 = (const float*)d_in[7];
    const float* bih1 = (const float*)d_in[8];
    const float* bhh1 = (const float*)d_in[9];
    const float* Wh0  = (const float*)d_in[10];
    const float* bh0  = (const float*)d_in[11];
    const float* Wh1  = (const float*)d_in[12];
    const float* bh1  = (const float*)d_in[13];
    const float* Wout = (const float*)d_in[14];

    float* ws = (float*)d_ws;
    float* zb = ws + OFF_ZB;
    float* P0 = ws + OFF_P0;
    u16*   pk = (u16*)(ws + OFF_P0);   // overlays P0, written after rnn consumed it
    float* out = (float*)d_out;

    p0_kernel<<<T_LEN - 1, 256, 0, stream>>>(x, Wih0, bih0, bhh0, P0);
    rnn_kernel<<<B_SZ, 64, 0, stream>>>(P0, h0in, Whh0, Wih1, Whh1, bih1, bhh1, zb, out);
    prep_pack<<<256, 256, 0, stream>>>(Wh1, Wh0, pk);
    ode_kernel<<<NSAMP / MBLK, 512, 0, stream>>>(zb, bh0, bh1, Wout, pk, out);
}

// Round 5
// 328.714 us; speedup vs baseline: 8.3962x; 1.1339x over previous
//
#include <hip/hip_runtime.h>
#include <math.h>

#define T_LEN 256
#define B_SZ  32
#define ZD    64
#define HD    256
#define NSAMP (B_SZ*(T_LEN-1))   // 8160
#define MBLK  32                 // samples per ODE block -> 255 blocks

typedef unsigned short u16;
typedef __attribute__((ext_vector_type(8))) _Float16 h8v;
typedef __attribute__((ext_vector_type(8))) unsigned short us8v;
typedef __attribute__((ext_vector_type(4))) float  f4v;

// ws layout (float offsets). Packs overlay P0 (prep runs AFTER rnn consumed P0).
#define SZ_ZB   (B_SZ*(T_LEN-1)*ZD)     // 522240
#define SZ_P0   ((T_LEN-1)*B_SZ*ZD)     // 522240
#define OFF_ZB  0
#define OFF_P0  (OFF_ZB + SZ_ZB)
// fp16 pack offsets in u16 units, based at (u16*)(ws + OFF_P0); 163840 u16 = 320KB <= P0 region
#define PK_WB  0         // Wh1^T fragments (phase B), 65536
#define PK_WC  65536     // Wh1 fragments (phase C), 65536
#define PK_WA  131072    // Wh0^T fragments (phase A), 16384
#define PK_WD  147456    // Wh0 fragments (phase D), 16384

__device__ __forceinline__ u16 f2h(float x) {
    _Float16 h = (_Float16)x;
    return __builtin_bit_cast(u16, h);
}
__device__ __forceinline__ float fast_tanh(float x) {
    float xc = fminf(fmaxf(x, -18.f), 18.f);
    float e2 = __builtin_amdgcn_exp2f(xc * 2.8853900817779268f);  // e^(2x)
    return (e2 - 1.f) * __builtin_amdgcn_rcpf(e2 + 1.f);
}
__device__ __forceinline__ f4v mfma16h(h8v a, h8v b, f4v c) {
    return __builtin_amdgcn_mfma_f32_16x16x32_f16(a, b, c, 0, 0, 0);
}
__device__ __forceinline__ h8v lds_frag(const u16* buf, int byt) {
    return *(const h8v*)((const char*)buf + byt);
}
__device__ __forceinline__ void store_h(u16* buf, int byt, float v) {
    *(u16*)((char*)buf + byt) = f2h(v);
}

// Yoshida coefficients * h_step (h=0.02). e%7: even=drift(+cs*h on q from dHp), odd=kick(-ds*h on p from dHq)
__device__ __constant__ float c_coef[7] = {
     0.013512071919596578f,
    -0.027024143839193156f,
    -0.003512071919596575f,
     0.034048287678386313f,
    -0.003512071919596575f,
    -0.027024143839193156f,
     0.013512071919596578f
};

// ---------------- prep: pack fp16 weights into MFMA B-fragment order ----------
// frag (nt,ks): lane = lg*16+col16 holds B[ks*32+lg*8+i][nt*16+col16], i=0..7
// idx = ((nt*KS + ks)*64 + lane)*8 + i
__global__ __launch_bounds__(256) void prep_pack(
    const float* __restrict__ Wh1, const float* __restrict__ Wh0, u16* __restrict__ pk)
{
    int i = blockIdx.x * 256 + threadIdx.x;      // 0..65535
    u16 h = f2h(Wh1[i]);
    {   // WB: B[k][n] = Wh1[n][k]; n=i>>8, k=i&255 (KS=8)
        int n = i >> 8, k = i & 255;
        int idx = ((((n >> 4) * 8 + (k >> 5)) * 64) + ((k >> 3) & 3) * 16 + (n & 15)) * 8 + (k & 7);
        pk[PK_WB + idx] = h;
    }
    {   // WC: B[k][n] = Wh1[k][n]; k=i>>8, n=i&255 (KS=8)
        int k = i >> 8, n = i & 255;
        int idx = ((((n >> 4) * 8 + (k >> 5)) * 64) + ((k >> 3) & 3) * 16 + (n & 15)) * 8 + (k & 7);
        pk[PK_WC + idx] = h;
    }
    if (i < HD * ZD) {
        u16 h0 = f2h(Wh0[i]);                    // Wh0[256][64]
        {   // WA: B[k][n] = Wh0[n][k]; n=i>>6 (0..255), k=i&63 (KS=2)
            int n = i >> 6, k = i & 63;
            int idx = ((((n >> 4) * 2 + (k >> 5)) * 64) + ((k >> 3) & 3) * 16 + (n & 15)) * 8 + (k & 7);
            pk[PK_WA + idx] = h0;
        }
        {   // WD: B[k][n] = Wh0[k][n]; k=i>>6, n=i&63 (KS=8, NT=4)
            int k = i >> 6, n = i & 63;
            int idx = ((((n >> 4) * 8 + (k >> 5)) * 64) + ((k >> 3) & 3) * 16 + (n & 15)) * 8 + (k & 7);
            pk[PK_WD + idx] = h0;
        }
    }
}

// ---------------- P0 = x[:,255-s,:] @ Wih0^T + bih0 + bhh0,  P0[s][b][j] -------
__global__ __launch_bounds__(256) void p0_kernel(
    const float* __restrict__ x, const float* __restrict__ Wih0,
    const float* __restrict__ bih0, const float* __restrict__ bhh0,
    float* __restrict__ P0)
{
    __shared__ float xs[B_SZ * 128];
    int s = blockIdx.x;
    int t = (T_LEN - 1) - s;
    int tid = threadIdx.x;
#pragma unroll
    for (int p = 0; p < 4; ++p) {
        int idx4 = tid + p * 256;
        int b = idx4 >> 5;
        int k = (idx4 & 31) * 4;
        *(float4*)&xs[b * 128 + k] = *(const float4*)&x[b * (T_LEN * 128) + t * 128 + k];
    }
    int j = tid & 63, bq = tid >> 6;
    float wr[128];
#pragma unroll
    for (int k4 = 0; k4 < 32; ++k4) {
        float4 v = *(const float4*)&Wih0[j * 128 + k4 * 4];
        wr[k4*4+0]=v.x; wr[k4*4+1]=v.y; wr[k4*4+2]=v.z; wr[k4*4+3]=v.w;
    }
    float bias = bih0[j] + bhh0[j];
    __syncthreads();
    for (int p = 0; p < 8; ++p) {
        int b = bq * 8 + p;
        float a0 = bias, a1 = 0.f;
#pragma unroll
        for (int k4 = 0; k4 < 32; ++k4) {
            float4 v = *(const float4*)&xs[b * 128 + k4 * 4];
            a0 += v.x * wr[k4*4+0] + v.y * wr[k4*4+1];
            a1 += v.z * wr[k4*4+2] + v.w * wr[k4*4+3];
        }
        P0[(s * B_SZ + b) * ZD + j] = a0 + a1;
    }
}

// ---------------- RNN scan: 2-wave pipelined (layer0 || layer1), dbuf LDS -----
// Tick s: wave0 computes y0[s+1] = tanh(P0[s+1] + Whh0.y0[s])   (s<254)
//         wave1 computes y1[s]   = tanh(b1 + Wih1.y0[s] + Whh1.y1[s-1])
// One barrier per tick; h0/h1 double-buffered in LDS.
__global__ __launch_bounds__(128, 1) void rnn_kernel(
    const float* __restrict__ P0, const float* __restrict__ h0in,
    const float* __restrict__ Whh0, const float* __restrict__ Wih1,
    const float* __restrict__ Whh1, const float* __restrict__ bih1,
    const float* __restrict__ bhh1,
    float* __restrict__ zbuf, float* __restrict__ out)
{
    __shared__ float h0buf[2][ZD];
    __shared__ float h1buf[2][ZD];
    const int b = blockIdx.x;
    const int tid = threadIdx.x;
    const int w = tid >> 6, j = tid & 63;

    float wA[ZD];           // wave0: Whh0 row j | wave1: Wih1 row j
    float wB[ZD];           // wave1 only: Whh1 row j
    float a_cur = 0.f, a_nxt = 0.f, bias1 = 0.f;

    if (w == 0) {
#pragma unroll
        for (int k4 = 0; k4 < 16; ++k4) {
            float4 v = *(const float4*)&Whh0[j * ZD + k4 * 4];
            wA[k4*4+0]=v.x; wA[k4*4+1]=v.y; wA[k4*4+2]=v.z; wA[k4*4+3]=v.w;
        }
        // prologue: y0[0] = tanh(P0[0] + Whh0 . h0init)
        float c0 = P0[(0 * B_SZ + b) * ZD + j], c1 = 0.f, c2 = 0.f, c3 = 0.f;
#pragma unroll
        for (int k4 = 0; k4 < 16; ++k4) {
            float4 v = *(const float4*)&h0in[k4 * 4];
            c0 += v.x * wA[k4*4+0]; c1 += v.y * wA[k4*4+1];
            c2 += v.z * wA[k4*4+2]; c3 += v.w * wA[k4*4+3];
        }
        h0buf[0][j] = fast_tanh((c0 + c1) + (c2 + c3));
        a_cur = P0[(1 * B_SZ + b) * ZD + j];
        a_nxt = P0[(2 * B_SZ + b) * ZD + j];
    } else {
#pragma unroll
        for (int k4 = 0; k4 < 16; ++k4) {
            float4 v = *(const float4*)&Wih1[j * ZD + k4 * 4];
            wA[k4*4+0]=v.x; wA[k4*4+1]=v.y; wA[k4*4+2]=v.z; wA[k4*4+3]=v.w;
            v = *(const float4*)&Whh1[j * ZD + k4 * 4];
            wB[k4*4+0]=v.x; wB[k4*4+1]=v.y; wB[k4*4+2]=v.z; wB[k4*4+3]=v.w;
        }
        bias1 = bih1[j] + bhh1[j];
        h1buf[0][j] = h0in[ZD + j];
    }
    __syncthreads();

    for (int s = 0; s < T_LEN - 1; ++s) {
        int p = s & 1;
        if (w == 0) {
            if (s < T_LEN - 2) {
                float a_new = (s + 3 <= T_LEN - 2) ? P0[((s + 3) * B_SZ + b) * ZD + j] : 0.f;
                float c0 = a_cur, c1 = 0.f, c2 = 0.f, c3 = 0.f;
#pragma unroll
                for (int k4 = 0; k4 < 16; ++k4) {
                    float4 v = *(const float4*)&h0buf[p][k4 * 4];
                    c0 += v.x * wA[k4*4+0]; c1 += v.y * wA[k4*4+1];
                    c2 += v.z * wA[k4*4+2]; c3 += v.w * wA[k4*4+3];
                }
                h0buf[p ^ 1][j] = fast_tanh((c0 + c1) + (c2 + c3));
                a_cur = a_nxt; a_nxt = a_new;
            }
        } else {
            float c0 = bias1, c1 = 0.f, c2 = 0.f, c3 = 0.f;
#pragma unroll
            for (int k4 = 0; k4 < 16; ++k4) {
                float4 v = *(const float4*)&h0buf[p][k4 * 4];
                c0 += v.x * wA[k4*4+0]; c1 += v.y * wA[k4*4+1];
                c2 += v.z * wA[k4*4+2]; c3 += v.w * wA[k4*4+3];
                float4 g = *(const float4*)&h1buf[p][k4 * 4];
                c0 += g.x * wB[k4*4+0]; c1 += g.y * wB[k4*4+1];
                c2 += g.z * wB[k4*4+2]; c3 += g.w * wB[k4*4+3];
            }
            float hn1 = fast_tanh((c0 + c1) + (c2 + c3));
            h1buf[p ^ 1][j] = hn1;
            zbuf[(b * (T_LEN - 1) + (T_LEN - 2 - s)) * ZD + j] = hn1;
            if (s == 0)
                out[(b * T_LEN + (T_LEN - 1)) * ZD + j] = hn1;
        }
        __syncthreads();
    }
}

// ---------------- ODE: fp16 MFMA, weights resident (VGPR+LDS), 512 thr --------
__global__ __launch_bounds__(512, 1) void ode_kernel(
    const float* __restrict__ zbuf,
    const float* __restrict__ bh0, const float* __restrict__ bh1,
    const float* __restrict__ Wout, const u16* __restrict__ pk,
    float* __restrict__ out)
{
    __shared__ __align__(16) u16 sWA[16384];   // 32KB, WA frags
    __shared__ __align__(16) u16 sWD[16384];   // 32KB, WD frags
    __shared__ __align__(16) u16 aA[32 * 256]; // 16KB, swizzled fp16 activations
    __shared__ __align__(16) u16 aB[32 * 256]; // 16KB
    __shared__ __align__(16) u16 zh[32 * 64];  // 4KB, swizzled fp16 z
    __shared__ __align__(16) float zq[32 * 64];// 8KB, fp32 z state

    const int tid  = threadIdx.x;
    const int w    = tid >> 6, lane = tid & 63;
    const int l15  = lane & 15, lg = lane >> 4;
    const int base = blockIdx.x * MBLK;

    // ---- load Wh1 fragments into VGPRs (per wave: 2 nt-tiles each for B and C)
    h8v regWB[2][8], regWC[2][8];
    {
        const h8v* pWB = (const h8v*)(pk + PK_WB);
        const h8v* pWC = (const h8v*)(pk + PK_WC);
#pragma unroll
        for (int t = 0; t < 2; ++t)
#pragma unroll
            for (int ks = 0; ks < 8; ++ks) {
                int fi = ((w * 2 + t) * 8 + ks) * 64 + lane;
                regWB[t][ks] = pWB[fi];
                regWC[t][ks] = pWC[fi];
            }
    }
    // ---- stage WA/WD into LDS (pack order)
    {
        const us8v* gA = (const us8v*)(pk + PK_WA);
        const us8v* gD = (const us8v*)(pk + PK_WD);
#pragma unroll
        for (int r = 0; r < 4; ++r) {
            int idx = tid + r * 512;             // 2048 vec8 per 32KB
            ((us8v*)sWA)[idx] = gA[idx];
            ((us8v*)sWD)[idx] = gD[idx];
        }
    }

    float bh0v[2], bh1v[2], wov[2];
#pragma unroll
    for (int t = 0; t < 2; ++t) {
        int col = (w * 2 + t) * 16 + l15;
        bh0v[t] = bh0[col]; bh1v[t] = bh1[col]; wov[t] = Wout[col];
    }

    // ---- stage z tile (32x64): zq f32 + zh swizzled fp16
    {
        int m = tid >> 4, c4 = tid & 15;
        float4 v = *(const float4*)&zbuf[(size_t)(base + m) * ZD + c4 * 4];
        *(float4*)&zq[m * 64 + c4 * 4] = v;
        ushort4 hh;
        hh.x = f2h(v.x); hh.y = f2h(v.y); hh.z = f2h(v.z); hh.w = f2h(v.w);
        int byt = (m * 128 + c4 * 8) ^ ((m & 7) << 4);
        *(ushort4*)((char*)zh + byt) = hh;
    }
    __syncthreads();

#pragma unroll 1
    for (int e = 0; e < 28; ++e) {
        int ei = e % 7;
        f4v acc[2][2];
#pragma unroll
        for (int mt = 0; mt < 2; ++mt)
#pragma unroll
            for (int t = 0; t < 2; ++t) acc[mt][t] = f4v{0.f, 0.f, 0.f, 0.f};

        // ---- Phase A: pre0 = z @ Wh0^T (K=64, N=256; wave w owns nt=2w,2w+1)
#pragma unroll
        for (int ks = 0; ks < 2; ++ks) {
            h8v az[2];
#pragma unroll
            for (int mt = 0; mt < 2; ++mt) {
                int byt = ((mt * 16 + l15) * 128 + ks * 64 + lg * 16) ^ ((l15 & 7) << 4);
                az[mt] = lds_frag(zh, byt);
            }
#pragma unroll
            for (int t = 0; t < 2; ++t) {
                h8v bw = lds_frag(sWA, (((w * 2 + t) * 2 + ks) * 64 + lane) * 16);
#pragma unroll
                for (int mt = 0; mt < 2; ++mt)
                    acc[mt][t] = mfma16h(az[mt], bw, acc[mt][t]);
            }
        }
        float h0reg[2][2][4];
#pragma unroll
        for (int mt = 0; mt < 2; ++mt)
#pragma unroll
            for (int t = 0; t < 2; ++t)
#pragma unroll
                for (int r = 0; r < 4; ++r) {
                    float tv = fast_tanh(acc[mt][t][r] + bh0v[t]);
                    h0reg[mt][t][r] = tv;
                    int row = mt * 16 + lg * 4 + r;
                    int col = (w * 2 + t) * 16 + l15;
                    store_h(aA, (row * 512 + col * 2) ^ ((row & 7) << 4), tv);
                }
        __syncthreads();

        // ---- Phase B: pre1 = h0 @ Wh1^T; g = Wout*(1-tanh^2)
#pragma unroll
        for (int mt = 0; mt < 2; ++mt)
#pragma unroll
            for (int t = 0; t < 2; ++t) acc[mt][t] = f4v{0.f, 0.f, 0.f, 0.f};
#pragma unroll
        for (int ks = 0; ks < 8; ++ks) {
            h8v ah[2];
#pragma unroll
            for (int mt = 0; mt < 2; ++mt) {
                int byt = ((mt * 16 + l15) * 512 + ks * 64 + lg * 16) ^ ((l15 & 7) << 4);
                ah[mt] = lds_frag(aA, byt);
            }
#pragma unroll
            for (int t = 0; t < 2; ++t)
#pragma unroll
                for (int mt = 0; mt < 2; ++mt)
                    acc[mt][t] = mfma16h(ah[mt], regWB[t][ks], acc[mt][t]);
        }
#pragma unroll
        for (int mt = 0; mt < 2; ++mt)
#pragma unroll
            for (int t = 0; t < 2; ++t)
#pragma unroll
                for (int r = 0; r < 4; ++r) {
                    float tv = fast_tanh(acc[mt][t][r] + bh1v[t]);
                    float g = wov[t] * (1.f - tv * tv);
                    int row = mt * 16 + lg * 4 + r;
                    int col = (w * 2 + t) * 16 + l15;
                    store_h(aB, (row * 512 + col * 2) ^ ((row & 7) << 4), g);
                }
        __syncthreads();

        // ---- Phase C: u = (g @ Wh1) * (1 - h0^2), overwrite aA
#pragma unroll
        for (int mt = 0; mt < 2; ++mt)
#pragma unroll
            for (int t = 0; t < 2; ++t) acc[mt][t] = f4v{0.f, 0.f, 0.f, 0.f};
#pragma unroll
        for (int ks = 0; ks < 8; ++ks) {
            h8v ah[2];
#pragma unroll
            for (int mt = 0; mt < 2; ++mt) {
                int byt = ((mt * 16 + l15) * 512 + ks * 64 + lg * 16) ^ ((l15 & 7) << 4);
                ah[mt] = lds_frag(aB, byt);
            }
#pragma unroll
            for (int t = 0; t < 2; ++t)
#pragma unroll
                for (int mt = 0; mt < 2; ++mt)
                    acc[mt][t] = mfma16h(ah[mt], regWC[t][ks], acc[mt][t]);
        }
#pragma unroll
        for (int mt = 0; mt < 2; ++mt)
#pragma unroll
            for (int t = 0; t < 2; ++t)
#pragma unroll
                for (int r = 0; r < 4; ++r) {
                    float hv = h0reg[mt][t][r];
                    float u = acc[mt][t][r] * (1.f - hv * hv);
                    int row = mt * 16 + lg * 4 + r;
                    int col = (w * 2 + t) * 16 + l15;
                    store_h(aA, (row * 512 + col * 2) ^ ((row & 7) << 4), u);
                }
        __syncthreads();

        // ---- Phase D (waves 4-7): dz = u @ Wh0 (N=64); update zq/zh
        if (w >= 4) {
            int nt = w - 4;
            f4v accd[2];
            accd[0] = f4v{0.f, 0.f, 0.f, 0.f};
            accd[1] = f4v{0.f, 0.f, 0.f, 0.f};
#pragma unroll
            for (int ks = 0; ks < 8; ++ks) {
                h8v ah[2];
#pragma unroll
                for (int mt = 0; mt < 2; ++mt) {
                    int byt = ((mt * 16 + l15) * 512 + ks * 64 + lg * 16) ^ ((l15 & 7) << 4);
                    ah[mt] = lds_frag(aA, byt);
                }
                h8v bw = lds_frag(sWD, ((nt * 8 + ks) * 64 + lane) * 16);
#pragma unroll
                for (int mt = 0; mt < 2; ++mt)
                    accd[mt] = mfma16h(ah[mt], bw, accd[mt]);
            }
            float cf = c_coef[ei];
            int col = nt * 16 + l15;
            bool drift = (ei & 1) == 0;
            bool active = drift ? (col >= 32) : (col < 32);
            int dcol = drift ? (col - 32) : (col + 32);
            if (active) {
#pragma unroll
                for (int mt = 0; mt < 2; ++mt)
#pragma unroll
                    for (int r = 0; r < 4; ++r) {
                        int row = mt * 16 + lg * 4 + r;
                        float nz = zq[row * 64 + dcol] + cf * accd[mt][r];
                        zq[row * 64 + dcol] = nz;
                        store_h(zh, (row * 128 + dcol * 2) ^ ((row & 7) << 4), nz);
                    }
            }
        }
        __syncthreads();
    }

    // ---- write out[b][tau][:] = z
    {
        int m = tid >> 4, c4 = tid & 15;
        int sidx = base + m;
        int b = sidx / 255;
        int tau = sidx - b * 255;
        float4 v = *(const float4*)&zq[m * 64 + c4 * 4];
        *(float4*)&out[((size_t)(b * T_LEN + tau)) * ZD + c4 * 4] = v;
    }
}

extern "C" void kernel_launch(void* const* d_in, const int* in_sizes, int n_in,
                              void* d_out, int out_size, void* d_ws, size_t ws_size,
                              hipStream_t stream)
{
    (void)in_sizes; (void)n_in; (void)out_size; (void)ws_size;
    const float* x    = (const float*)d_in[0];
    const float* h0in = (const float*)d_in[1];
    const float* Wih0 = (const float*)d_in[2];
    const float* Whh0 = (const float*)d_in[3];
    const float* bih0 = (const float*)d_in[4];
    const float* bhh0 = (const float*)d_in[5];
    const float* Wih1 = (const float*)d_in[6];
    const float* Whh1 = (const float*)d_in[7];
    const float* bih1 = (const float*)d_in[8];
    const float* bhh1 = (const float*)d_in[9];
    const float* Wh0  = (const float*)d_in[10];
    const float* bh0  = (const float*)d_in[11];
    const float* Wh1  = (const float*)d_in[12];
    const float* bh1  = (const float*)d_in[13];
    const float* Wout = (const float*)d_in[14];

    float* ws = (float*)d_ws;
    float* zb = ws + OFF_ZB;
    float* P0 = ws + OFF_P0;
    u16*   pk = (u16*)(ws + OFF_P0);   // overlays P0, written after rnn consumed it
    float* out = (float*)d_out;

    p0_kernel<<<T_LEN - 1, 256, 0, stream>>>(x, Wih0, bih0, bhh0, P0);
    rnn_kernel<<<B_SZ, 128, 0, stream>>>(P0, h0in, Whh0, Wih1, Whh1, bih1, bhh1, zb, out);
    prep_pack<<<256, 256, 0, stream>>>(Wh1, Wh0, pk);
    ode_kernel<<<NSAMP / MBLK, 512, 0, stream>>>(zb, bh0, bh1, Wout, pk, out);
}

// Round 6
// 314.342 us; speedup vs baseline: 8.7801x; 1.0457x over previous
//
#include <hip/hip_runtime.h>
#include <math.h>

#define T_LEN 256
#define B_SZ  32
#define ZD    64
#define HD    256
#define NSAMP (B_SZ*(T_LEN-1))   // 8160
#define MBLK  32                 // samples per ODE block -> 255 blocks

typedef unsigned short u16;
typedef __attribute__((ext_vector_type(8))) _Float16 h8v;
typedef __attribute__((ext_vector_type(8))) unsigned short us8v;
typedef __attribute__((ext_vector_type(4))) float  f4v;

// ws layout (float offsets). Packs overlay P0 (prep runs AFTER rnn consumed P0).
#define SZ_ZB   (B_SZ*(T_LEN-1)*ZD)     // 522240
#define SZ_P0   ((T_LEN-1)*B_SZ*ZD)     // 522240 (P0 in C-fragment pack order)
#define OFF_ZB  0
#define OFF_P0  (OFF_ZB + SZ_ZB)
// fp16 pack offsets in u16 units, based at (u16*)(ws + OFF_P0); 163840 u16 = 320KB <= P0 region
#define PK_WB  0         // Wh1^T fragments (phase B), 65536
#define PK_WC  65536     // Wh1 fragments (phase C), 65536
#define PK_WA  131072    // Wh0^T fragments (phase A), 16384
#define PK_WD  147456    // Wh0 fragments (phase D), 16384

__device__ __forceinline__ u16 f2h(float x) {
    _Float16 h = (_Float16)x;
    return __builtin_bit_cast(u16, h);
}
__device__ __forceinline__ float fast_tanh(float x) {
    float xc = fminf(fmaxf(x, -18.f), 18.f);
    float e2 = __builtin_amdgcn_exp2f(xc * 2.8853900817779268f);  // e^(2x)
    return (e2 - 1.f) * __builtin_amdgcn_rcpf(e2 + 1.f);
}
__device__ __forceinline__ f4v mfma16h(h8v a, h8v b, f4v c) {
    return __builtin_amdgcn_mfma_f32_16x16x32_f16(a, b, c, 0, 0, 0);
}
__device__ __forceinline__ h8v lds_frag(const u16* buf, int byt) {
    return *(const h8v*)((const char*)buf + byt);
}
__device__ __forceinline__ void store_h(u16* buf, int byt, float v) {
    *(u16*)((char*)buf + byt) = f2h(v);
}

// Yoshida coefficients * h_step (h=0.02). e%7: even=drift(+cs*h on q from dHp), odd=kick(-ds*h on p from dHq)
__device__ __constant__ float c_coef[7] = {
     0.013512071919596578f,
    -0.027024143839193156f,
    -0.003512071919596575f,
     0.034048287678386313f,
    -0.003512071919596575f,
    -0.027024143839193156f,
     0.013512071919596578f
};

// ---------------- prep: pack fp16 weights into MFMA B-fragment order ----------
// frag (nt,ks): lane = lg*16+col16 holds B[ks*32+lg*8+i][nt*16+col16], i=0..7
// idx = ((nt*KS + ks)*64 + lane)*8 + i
__global__ __launch_bounds__(256) void prep_pack(
    const float* __restrict__ Wh1, const float* __restrict__ Wh0, u16* __restrict__ pk)
{
    int i = blockIdx.x * 256 + threadIdx.x;      // 0..65535
    u16 h = f2h(Wh1[i]);
    {   // WB: B[k][n] = Wh1[n][k]; n=i>>8, k=i&255 (KS=8)
        int n = i >> 8, k = i & 255;
        int idx = ((((n >> 4) * 8 + (k >> 5)) * 64) + ((k >> 3) & 3) * 16 + (n & 15)) * 8 + (k & 7);
        pk[PK_WB + idx] = h;
    }
    {   // WC: B[k][n] = Wh1[k][n]; k=i>>8, n=i&255 (KS=8)
        int k = i >> 8, n = i & 255;
        int idx = ((((n >> 4) * 8 + (k >> 5)) * 64) + ((k >> 3) & 3) * 16 + (n & 15)) * 8 + (k & 7);
        pk[PK_WC + idx] = h;
    }
    if (i < HD * ZD) {
        u16 h0 = f2h(Wh0[i]);                    // Wh0[256][64]
        {   // WA: B[k][n] = Wh0[n][k]; n=i>>6 (0..255), k=i&63 (KS=2)
            int n = i >> 6, k = i & 63;
            int idx = ((((n >> 4) * 2 + (k >> 5)) * 64) + ((k >> 3) & 3) * 16 + (n & 15)) * 8 + (k & 7);
            pk[PK_WA + idx] = h0;
        }
        {   // WD: B[k][n] = Wh0[k][n]; k=i>>6, n=i&63 (KS=8, NT=4)
            int k = i >> 6, n = i & 63;
            int idx = ((((n >> 4) * 8 + (k >> 5)) * 64) + ((k >> 3) & 3) * 16 + (n & 15)) * 8 + (k & 7);
            pk[PK_WD + idx] = h0;
        }
    }
}

// ---------------- P0 in C-fragment pack order -------------------------------
// P0pack[((s*4 + nt)*64 + lane)*8 + mt*4 + r] = P0[s][b=mt*16+lg*4+r][j=nt*16+l15]
// where lane = lg*16 + l15.
__global__ __launch_bounds__(256) void p0_kernel(
    const float* __restrict__ x, const float* __restrict__ Wih0,
    const float* __restrict__ bih0, const float* __restrict__ bhh0,
    float* __restrict__ P0pack)
{
    __shared__ float xs[B_SZ * 128];
    int s = blockIdx.x;
    int t = (T_LEN - 1) - s;
    int tid = threadIdx.x;
#pragma unroll
    for (int p = 0; p < 4; ++p) {
        int idx4 = tid + p * 256;
        int b = idx4 >> 5;
        int k = (idx4 & 31) * 4;
        *(float4*)&xs[b * 128 + k] = *(const float4*)&x[b * (T_LEN * 128) + t * 128 + k];
    }
    int j = tid & 63, bq = tid >> 6;
    float wr[128];
#pragma unroll
    for (int k4 = 0; k4 < 32; ++k4) {
        float4 v = *(const float4*)&Wih0[j * 128 + k4 * 4];
        wr[k4*4+0]=v.x; wr[k4*4+1]=v.y; wr[k4*4+2]=v.z; wr[k4*4+3]=v.w;
    }
    float bias = bih0[j] + bhh0[j];
    int nt = j >> 4, l15 = j & 15;
    __syncthreads();
    for (int p = 0; p < 8; ++p) {
        int b = bq * 8 + p;
        float a0 = bias, a1 = 0.f;
#pragma unroll
        for (int k4 = 0; k4 < 32; ++k4) {
            float4 v = *(const float4*)&xs[b * 128 + k4 * 4];
            a0 += v.x * wr[k4*4+0] + v.y * wr[k4*4+1];
            a1 += v.z * wr[k4*4+2] + v.w * wr[k4*4+3];
        }
        int mt = b >> 4, ri = b & 15, lg = ri >> 2, r = ri & 3;
        int lane = lg * 16 + l15;
        P0pack[((s * 4 + nt) * 64 + lane) * 8 + mt * 4 + r] = a0 + a1;
    }
}

// ---------------- RNN scan: 1 block, 8 waves, MFMA recurrence ----------------
// Waves 0-3: H0[s+1] = tanh(P0[s+1] + H0[s] @ Whh0^T)   (nt = w)
// Waves 4-7: H1[s]   = tanh(b1 + H0[s] @ Wih1^T + H1[s-1] @ Whh1^T)  (nt = w-4)
// One barrier per tick. H-state fp16 in XOR-swizzled LDS.
__global__ __launch_bounds__(512, 1) void rnn_kernel(
    const float* __restrict__ P0pack, const float* __restrict__ h0in,
    const float* __restrict__ Whh0, const float* __restrict__ Wih1,
    const float* __restrict__ Whh1, const float* __restrict__ bih1,
    const float* __restrict__ bhh1,
    float* __restrict__ zbuf, float* __restrict__ out)
{
    __shared__ __align__(16) u16 H0buf[2][32 * 64];
    __shared__ __align__(16) u16 H1buf[2][32 * 64];
    __shared__ float dvec[ZD];

    const int tid  = threadIdx.x;
    const int w    = tid >> 6, lane = tid & 63;
    const int l15  = lane & 15, lg = lane >> 4;
    const int nt   = w & 3;
    const int col  = nt * 16 + l15;
    const bool L0  = (w < 4);

    // ---- B-fragments in registers (loaded once, 8-16 VGPRs) ----
    h8v fA[2], fB[2];
    {
        const float* WAm = L0 ? Whh0 : Wih1;
#pragma unroll
        for (int ks = 0; ks < 2; ++ks) {
            const float* src = &WAm[col * 64 + ks * 32 + lg * 8];
            float4 v0 = *(const float4*)&src[0];
            float4 v1 = *(const float4*)&src[4];
            h8v f;
            f[0]=(_Float16)v0.x; f[1]=(_Float16)v0.y; f[2]=(_Float16)v0.z; f[3]=(_Float16)v0.w;
            f[4]=(_Float16)v1.x; f[5]=(_Float16)v1.y; f[6]=(_Float16)v1.z; f[7]=(_Float16)v1.w;
            fA[ks] = f;
        }
        if (!L0) {
#pragma unroll
            for (int ks = 0; ks < 2; ++ks) {
                const float* src = &Whh1[col * 64 + ks * 32 + lg * 8];
                float4 v0 = *(const float4*)&src[0];
                float4 v1 = *(const float4*)&src[4];
                h8v f;
                f[0]=(_Float16)v0.x; f[1]=(_Float16)v0.y; f[2]=(_Float16)v0.z; f[3]=(_Float16)v0.w;
                f[4]=(_Float16)v1.x; f[5]=(_Float16)v1.y; f[6]=(_Float16)v1.z; f[7]=(_Float16)v1.w;
                fB[ks] = f;
            }
        } else {
            fB[0] = h8v{}; fB[1] = h8v{};
        }
    }
    float bias1 = L0 ? 0.f : (bih1[col] + bhh1[col]);

    // ---- prologue: dvec = Whh0 @ h0init ; H1[-1] = h0init[1] (all batches) ----
    if (tid < ZD) {
        float d = 0.f;
#pragma unroll 8
        for (int k = 0; k < ZD; ++k) d += Whh0[tid * ZD + k] * h0in[k];
        dvec[tid] = d;
    }
    {
        int row = tid >> 4, c = (tid & 15) * 4;
        ushort4 hh;
        hh.x = f2h(h0in[ZD + c]);     hh.y = f2h(h0in[ZD + c + 1]);
        hh.z = f2h(h0in[ZD + c + 2]); hh.w = f2h(h0in[ZD + c + 3]);
        int byt = (row * 128 + c * 2) ^ ((row & 7) << 4);
        *(ushort4*)((char*)H1buf[0] + byt) = hh;
    }
    __syncthreads();
    if (L0) {   // H0[0] = tanh(P0[0] + dvec)
        int base = ((0 * 4 + nt) * 64 + lane) * 8;
        float4 c0 = *(const float4*)&P0pack[base];
        float4 c1 = *(const float4*)&P0pack[base + 4];
        float dv = dvec[col];
        float vals[8] = {c0.x, c0.y, c0.z, c0.w, c1.x, c1.y, c1.z, c1.w};
#pragma unroll
        for (int i = 0; i < 8; ++i) {
            int mt = i >> 2, r = i & 3;
            int row = mt * 16 + lg * 4 + r;
            store_h(H0buf[0], (row * 128 + col * 2) ^ ((row & 7) << 4), fast_tanh(vals[i] + dv));
        }
    }
    // prefetch P[1], P[2]
    float4 ac0 = {0,0,0,0}, ac1 = {0,0,0,0}, an0 = {0,0,0,0}, an1 = {0,0,0,0};
    if (L0) {
        int b1 = ((1 * 4 + nt) * 64 + lane) * 8;
        ac0 = *(const float4*)&P0pack[b1]; ac1 = *(const float4*)&P0pack[b1 + 4];
        int b2 = ((2 * 4 + nt) * 64 + lane) * 8;
        an0 = *(const float4*)&P0pack[b2]; an1 = *(const float4*)&P0pack[b2 + 4];
    }
    __syncthreads();

    for (int s = 0; s < T_LEN - 1; ++s) {
        int p = s & 1;
        if (L0) {
            if (s < T_LEN - 2) {
                float4 aw0 = {0,0,0,0}, aw1 = {0,0,0,0};
                if (s + 3 <= T_LEN - 2) {
                    int bb = (((s + 3) * 4 + nt) * 64 + lane) * 8;
                    aw0 = *(const float4*)&P0pack[bb]; aw1 = *(const float4*)&P0pack[bb + 4];
                }
                f4v acc0 = {ac0.x, ac0.y, ac0.z, ac0.w};
                f4v acc1 = {ac1.x, ac1.y, ac1.z, ac1.w};
#pragma unroll
                for (int ks = 0; ks < 2; ++ks) {
                    h8v a0 = lds_frag(H0buf[p], ((l15) * 128 + ks * 64 + lg * 16) ^ ((l15 & 7) << 4));
                    h8v a1 = lds_frag(H0buf[p], ((16 + l15) * 128 + ks * 64 + lg * 16) ^ ((l15 & 7) << 4));
                    acc0 = mfma16h(a0, fA[ks], acc0);
                    acc1 = mfma16h(a1, fA[ks], acc1);
                }
#pragma unroll
                for (int r = 0; r < 4; ++r) {
                    int row0 = lg * 4 + r;
                    store_h(H0buf[p ^ 1], (row0 * 128 + col * 2) ^ ((row0 & 7) << 4), fast_tanh(acc0[r]));
                    int row1 = 16 + lg * 4 + r;
                    store_h(H0buf[p ^ 1], (row1 * 128 + col * 2) ^ ((row1 & 7) << 4), fast_tanh(acc1[r]));
                }
                ac0 = an0; ac1 = an1; an0 = aw0; an1 = aw1;
            }
        } else {
            f4v acc0 = {bias1, bias1, bias1, bias1};
            f4v acc1 = acc0;
#pragma unroll
            for (int ks = 0; ks < 2; ++ks) {
                h8v a0 = lds_frag(H0buf[p], ((l15) * 128 + ks * 64 + lg * 16) ^ ((l15 & 7) << 4));
                h8v a1 = lds_frag(H0buf[p], ((16 + l15) * 128 + ks * 64 + lg * 16) ^ ((l15 & 7) << 4));
                acc0 = mfma16h(a0, fA[ks], acc0);
                acc1 = mfma16h(a1, fA[ks], acc1);
                h8v g0 = lds_frag(H1buf[p], ((l15) * 128 + ks * 64 + lg * 16) ^ ((l15 & 7) << 4));
                h8v g1 = lds_frag(H1buf[p], ((16 + l15) * 128 + ks * 64 + lg * 16) ^ ((l15 & 7) << 4));
                acc0 = mfma16h(g0, fB[ks], acc0);
                acc1 = mfma16h(g1, fB[ks], acc1);
            }
            int tau = (T_LEN - 2) - s;
#pragma unroll
            for (int r = 0; r < 4; ++r) {
                float v0 = fast_tanh(acc0[r]);
                float v1 = fast_tanh(acc1[r]);
                int row0 = lg * 4 + r, row1 = 16 + lg * 4 + r;
                store_h(H1buf[p ^ 1], (row0 * 128 + col * 2) ^ ((row0 & 7) << 4), v0);
                store_h(H1buf[p ^ 1], (row1 * 128 + col * 2) ^ ((row1 & 7) << 4), v1);
                zbuf[(row0 * (T_LEN - 1) + tau) * ZD + col] = v0;
                zbuf[(row1 * (T_LEN - 1) + tau) * ZD + col] = v1;
                if (s == 0) {
                    out[(row0 * T_LEN + (T_LEN - 1)) * ZD + col] = v0;
                    out[(row1 * T_LEN + (T_LEN - 1)) * ZD + col] = v1;
                }
            }
        }
        __syncthreads();
    }
}

// ---------------- ODE: fp16 MFMA, weights resident (VGPR+LDS), 512 thr --------
__global__ __launch_bounds__(512, 1) void ode_kernel(
    const float* __restrict__ zbuf,
    const float* __restrict__ bh0, const float* __restrict__ bh1,
    const float* __restrict__ Wout, const u16* __restrict__ pk,
    float* __restrict__ out)
{
    __shared__ __align__(16) u16 sWA[16384];   // 32KB, WA frags
    __shared__ __align__(16) u16 sWD[16384];   // 32KB, WD frags
    __shared__ __align__(16) u16 aA[32 * 256]; // 16KB, swizzled fp16 activations
    __shared__ __align__(16) u16 aB[32 * 256]; // 16KB
    __shared__ __align__(16) u16 zh[32 * 64];  // 4KB, swizzled fp16 z
    __shared__ __align__(16) float zq[32 * 64];// 8KB, fp32 z state

    const int tid  = threadIdx.x;
    const int w    = tid >> 6, lane = tid & 63;
    const int l15  = lane & 15, lg = lane >> 4;
    const int base = blockIdx.x * MBLK;

    // ---- load Wh1 fragments into VGPRs (per wave: 2 nt-tiles each for B and C)
    h8v regWB[2][8], regWC[2][8];
    {
        const h8v* pWB = (const h8v*)(pk + PK_WB);
        const h8v* pWC = (const h8v*)(pk + PK_WC);
#pragma unroll
        for (int t = 0; t < 2; ++t)
#pragma unroll
            for (int ks = 0; ks < 8; ++ks) {
                int fi = ((w * 2 + t) * 8 + ks) * 64 + lane;
                regWB[t][ks] = pWB[fi];
                regWC[t][ks] = pWC[fi];
            }
    }
    // ---- stage WA/WD into LDS (pack order)
    {
        const us8v* gA = (const us8v*)(pk + PK_WA);
        const us8v* gD = (const us8v*)(pk + PK_WD);
#pragma unroll
        for (int r = 0; r < 4; ++r) {
            int idx = tid + r * 512;             // 2048 vec8 per 32KB
            ((us8v*)sWA)[idx] = gA[idx];
            ((us8v*)sWD)[idx] = gD[idx];
        }
    }

    float bh0v[2], bh1v[2], wov[2];
#pragma unroll
    for (int t = 0; t < 2; ++t) {
        int col = (w * 2 + t) * 16 + l15;
        bh0v[t] = bh0[col]; bh1v[t] = bh1[col]; wov[t] = Wout[col];
    }

    // ---- stage z tile (32x64): zq f32 + zh swizzled fp16
    {
        int m = tid >> 4, c4 = tid & 15;
        float4 v = *(const float4*)&zbuf[(size_t)(base + m) * ZD + c4 * 4];
        *(float4*)&zq[m * 64 + c4 * 4] = v;
        ushort4 hh;
        hh.x = f2h(v.x); hh.y = f2h(v.y); hh.z = f2h(v.z); hh.w = f2h(v.w);
        int byt = (m * 128 + c4 * 8) ^ ((m & 7) << 4);
        *(ushort4*)((char*)zh + byt) = hh;
    }
    __syncthreads();

#pragma unroll 1
    for (int e = 0; e < 28; ++e) {
        int ei = e % 7;
        f4v acc[2][2];
#pragma unroll
        for (int mt = 0; mt < 2; ++mt)
#pragma unroll
            for (int t = 0; t < 2; ++t) acc[mt][t] = f4v{0.f, 0.f, 0.f, 0.f};

        // ---- Phase A: pre0 = z @ Wh0^T (K=64, N=256; wave w owns nt=2w,2w+1)
#pragma unroll
        for (int ks = 0; ks < 2; ++ks) {
            h8v az[2];
#pragma unroll
            for (int mt = 0; mt < 2; ++mt) {
                int byt = ((mt * 16 + l15) * 128 + ks * 64 + lg * 16) ^ ((l15 & 7) << 4);
                az[mt] = lds_frag(zh, byt);
            }
#pragma unroll
            for (int t = 0; t < 2; ++t) {
                h8v bw = lds_frag(sWA, (((w * 2 + t) * 2 + ks) * 64 + lane) * 16);
#pragma unroll
                for (int mt = 0; mt < 2; ++mt)
                    acc[mt][t] = mfma16h(az[mt], bw, acc[mt][t]);
            }
        }
        float h0reg[2][2][4];
#pragma unroll
        for (int mt = 0; mt < 2; ++mt)
#pragma unroll
            for (int t = 0; t < 2; ++t)
#pragma unroll
                for (int r = 0; r < 4; ++r) {
                    float tv = fast_tanh(acc[mt][t][r] + bh0v[t]);
                    h0reg[mt][t][r] = tv;
                    int row = mt * 16 + lg * 4 + r;
                    int col = (w * 2 + t) * 16 + l15;
                    store_h(aA, (row * 512 + col * 2) ^ ((row & 7) << 4), tv);
                }
        __syncthreads();

        // ---- Phase B: pre1 = h0 @ Wh1^T; g = Wout*(1-tanh^2)
#pragma unroll
        for (int mt = 0; mt < 2; ++mt)
#pragma unroll
            for (int t = 0; t < 2; ++t) acc[mt][t] = f4v{0.f, 0.f, 0.f, 0.f};
#pragma unroll
        for (int ks = 0; ks < 8; ++ks) {
            h8v ah[2];
#pragma unroll
            for (int mt = 0; mt < 2; ++mt) {
                int byt = ((mt * 16 + l15) * 512 + ks * 64 + lg * 16) ^ ((l15 & 7) << 4);
                ah[mt] = lds_frag(aA, byt);
            }
#pragma unroll
            for (int t = 0; t < 2; ++t)
#pragma unroll
                for (int mt = 0; mt < 2; ++mt)
                    acc[mt][t] = mfma16h(ah[mt], regWB[t][ks], acc[mt][t]);
        }
#pragma unroll
        for (int mt = 0; mt < 2; ++mt)
#pragma unroll
            for (int t = 0; t < 2; ++t)
#pragma unroll
                for (int r = 0; r < 4; ++r) {
                    float tv = fast_tanh(acc[mt][t][r] + bh1v[t]);
                    float g = wov[t] * (1.f - tv * tv);
                    int row = mt * 16 + lg * 4 + r;
                    int col = (w * 2 + t) * 16 + l15;
                    store_h(aB, (row * 512 + col * 2) ^ ((row & 7) << 4), g);
                }
        __syncthreads();

        // ---- Phase C: u = (g @ Wh1) * (1 - h0^2), overwrite aA
#pragma unroll
        for (int mt = 0; mt < 2; ++mt)
#pragma unroll
            for (int t = 0; t < 2; ++t) acc[mt][t] = f4v{0.f, 0.f, 0.f, 0.f};
#pragma unroll
        for (int ks = 0; ks < 8; ++ks) {
            h8v ah[2];
#pragma unroll
            for (int mt = 0; mt < 2; ++mt) {
                int byt = ((mt * 16 + l15) * 512 + ks * 64 + lg * 16) ^ ((l15 & 7) << 4);
                ah[mt] = lds_frag(aB, byt);
            }
#pragma unroll
            for (int t = 0; t < 2; ++t)
#pragma unroll
                for (int mt = 0; mt < 2; ++mt)
                    acc[mt][t] = mfma16h(ah[mt], regWC[t][ks], acc[mt][t]);
        }
#pragma unroll
        for (int mt = 0; mt < 2; ++mt)
#pragma unroll
            for (int t = 0; t < 2; ++t)
#pragma unroll
                for (int r = 0; r < 4; ++r) {
                    float hv = h0reg[mt][t][r];
                    float u = acc[mt][t][r] * (1.f - hv * hv);
                    int row = mt * 16 + lg * 4 + r;
                    int col = (w * 2 + t) * 16 + l15;
                    store_h(aA, (row * 512 + col * 2) ^ ((row & 7) << 4), u);
                }
        __syncthreads();

        // ---- Phase D (waves 4-7): dz = u @ Wh0 (N=64); update zq/zh
        if (w >= 4) {
            int nt = w - 4;
            f4v accd[2];
            accd[0] = f4v{0.f, 0.f, 0.f, 0.f};
            accd[1] = f4v{0.f, 0.f, 0.f, 0.f};
#pragma unroll
            for (int ks = 0; ks < 8; ++ks) {
                h8v ah[2];
#pragma unroll
                for (int mt = 0; mt < 2; ++mt) {
                    int byt = ((mt * 16 + l15) * 512 + ks * 64 + lg * 16) ^ ((l15 & 7) << 4);
                    ah[mt] = lds_frag(aA, byt);
                }
                h8v bw = lds_frag(sWD, ((nt * 8 + ks) * 64 + lane) * 16);
#pragma unroll
                for (int mt = 0; mt < 2; ++mt)
                    accd[mt] = mfma16h(ah[mt], bw, accd[mt]);
            }
            float cf = c_coef[ei];
            int col = nt * 16 + l15;
            bool drift = (ei & 1) == 0;
            bool active = drift ? (col >= 32) : (col < 32);
            int dcol = drift ? (col - 32) : (col + 32);
            if (active) {
#pragma unroll
                for (int mt = 0; mt < 2; ++mt)
#pragma unroll
                    for (int r = 0; r < 4; ++r) {
                        int row = mt * 16 + lg * 4 + r;
                        float nz = zq[row * 64 + dcol] + cf * accd[mt][r];
                        zq[row * 64 + dcol] = nz;
                        store_h(zh, (row * 128 + dcol * 2) ^ ((row & 7) << 4), nz);
                    }
            }
        }
        __syncthreads();
    }

    // ---- write out[b][tau][:] = z
    {
        int m = tid >> 4, c4 = tid & 15;
        int sidx = base + m;
        int b = sidx / 255;
        int tau = sidx - b * 255;
        float4 v = *(const float4*)&zq[m * 64 + c4 * 4];
        *(float4*)&out[((size_t)(b * T_LEN + tau)) * ZD + c4 * 4] = v;
    }
}

extern "C" void kernel_launch(void* const* d_in, const int* in_sizes, int n_in,
                              void* d_out, int out_size, void* d_ws, size_t ws_size,
                              hipStream_t stream)
{
    (void)in_sizes; (void)n_in; (void)out_size; (void)ws_size;
    const float* x    = (const float*)d_in[0];
    const float* h0in = (const float*)d_in[1];
    const float* Wih0 = (const float*)d_in[2];
    const float* Whh0 = (const float*)d_in[3];
    const float* bih0 = (const float*)d_in[4];
    const float* bhh0 = (const float*)d_in[5];
    const float* Wih1 = (const float*)d_in[6];
    const float* Whh1 = (const float*)d_in[7];
    const float* bih1 = (const float*)d_in[8];
    const float* bhh1 = (const float*)d_in[9];
    const float* Wh0  = (const float*)d_in[10];
    const float* bh0  = (const float*)d_in[11];
    const float* Wh1  = (const float*)d_in[12];
    const float* bh1  = (const float*)d_in[13];
    const float* Wout = (const float*)d_in[14];

    float* ws = (float*)d_ws;
    float* zb = ws + OFF_ZB;
    float* P0 = ws + OFF_P0;
    u16*   pk = (u16*)(ws + OFF_P0);   // overlays P0, written after rnn consumed it
    float* out = (float*)d_out;

    p0_kernel<<<T_LEN - 1, 256, 0, stream>>>(x, Wih0, bih0, bhh0, P0);
    rnn_kernel<<<1, 512, 0, stream>>>(P0, h0in, Whh0, Wih1, Whh1, bih1, bhh1, zb, out);
    prep_pack<<<256, 256, 0, stream>>>(Wh1, Wh0, pk);
    ode_kernel<<<NSAMP / MBLK, 512, 0, stream>>>(zb, bh0, bh1, Wout, pk, out);
}